// Round 1
// baseline (6719.525 us; speedup 1.0000x reference)
//
#include <hip/hip_runtime.h>

// Generator_78683800862785: attention+LSTM decoder, BS=1024, T=30.
// R1: LAUNCH-BOUND FIX. Previous best (4055us) ran 5 kernels/step x 30 steps;
// real work is ~25us/step but measured ~131us/step => ~20us/launch overhead.
// This version fuses the whole T-loop into ONE persistent kernel (256 blocks x
// 512 thr, <=1 block/CU by LDS => co-resident) with in-kernel global barriers
// (two-level atomic arrival + __threadfence for cross-XCD L2 coherence).
// All inter-phase deps are contained in 64-batch groups (block group = blk>>4).
// Also: LSTM c-state kept in registers across all 30 steps; fixed latent
// h-buffer read/write race of the baseline by writing h(t) to buffers disjoint
// from the h(t-1) GEMM inputs and copying one phase later.

#define DEVI __device__ __forceinline__

typedef _Float16 f16x8 __attribute__((ext_vector_type(8)));
typedef _Float16 f16x4 __attribute__((ext_vector_type(4)));
typedef float    f32x4 __attribute__((ext_vector_type(4)));

#define BSZ 1024
#define SEQ 100
#define ENC 256
#define HID 512
#define LAT 64
#define TT  30

// ---------------------------------------------------------------- utilities
DEVI float lrelu(float v) { return v >= 0.f ? v : 0.2f * v; }
DEVI float sigm(float x)  { return 1.f / (1.f + __expf(-x)); }
DEVI float tanh_f(float x){ return 1.f - 2.f / (1.f + __expf(2.f * x)); }

// ---------------------------------------------------------------- setup kernels
__global__ __launch_bounds__(256) void zero_ws(uint4* __restrict__ p) {
    uint4 z; z.x = z.y = z.z = z.w = 0u;
    p[(size_t)blockIdx.x * 256 + threadIdx.x] = z;
}

__global__ __launch_bounds__(256) void conv_enc(const float4* __restrict__ src,
                                                f16x4* __restrict__ dst) {
    size_t i = (size_t)blockIdx.x * 256 + threadIdx.x;
    float4 v = src[i];
    f16x4 h;
    h.x = (_Float16)v.x; h.y = (_Float16)v.y; h.z = (_Float16)v.z; h.w = (_Float16)v.w;
    dst[i] = h;
}

// C[ne,h] = scale * sum_d k_w[n*128+d, e] * q_w[n*128+d, h]   (fp16 out)
// d[ne]   = scale * sum_d k_w[n*128+d, e] * q_b[n*128+d]
__global__ __launch_bounds__(256) void prep_qk(const float* __restrict__ k_w,
                                               const float* __restrict__ q_w,
                                               const float* __restrict__ q_b,
                                               _Float16* __restrict__ C_h,
                                               float* __restrict__ d_f,
                                               _Float16* __restrict__ d_h) {
    const int ne = blockIdx.x, n = ne >> 8, e = ne & 255, tid = threadIdx.x;
    const float scale = 0.08838834764831845f;  // 1/sqrt(128)
    float a0 = 0.f, a1 = 0.f;
    for (int dd = 0; dd < 128; ++dd) {
        float kv = k_w[(n * 128 + dd) * 256 + e];
        a0 += kv * q_w[(n * 128 + dd) * 512 + tid];
        a1 += kv * q_w[(n * 128 + dd) * 512 + 256 + tid];
    }
    C_h[(size_t)ne * 512 + tid]       = (_Float16)(scale * a0);
    C_h[(size_t)ne * 512 + 256 + tid] = (_Float16)(scale * a1);
    float pq = (tid < 128) ? k_w[(n * 128 + tid) * 256 + e] * q_b[n * 128 + tid] : 0.f;
    #pragma unroll
    for (int off = 32; off; off >>= 1) pq += __shfl_down(pq, off);
    __shared__ float red[4];
    if ((tid & 63) == 0) red[tid >> 6] = pq;
    __syncthreads();
    if (tid == 0) {
        float s = scale * (red[0] + red[1] + red[2] + red[3]);
        d_f[ne] = s; d_h[ne] = (_Float16)s;
    }
}

// A[h,k] = sum_m fc1_w[h, m] * out_w[m, k]
__global__ __launch_bounds__(256) void prep_A(const float* __restrict__ fc1_w,
                                              const float* __restrict__ out_w,
                                              float* __restrict__ A) {
    const int h = blockIdx.x, tid = threadIdx.x;
    float a0 = 0.f, a1 = 0.f;
    for (int m = 0; m < 512; ++m) {
        float fv = fc1_w[h * 576 + m];
        a0 += fv * out_w[m * 512 + tid];
        a1 += fv * out_w[m * 512 + 256 + tid];
    }
    A[(size_t)h * 512 + tid]       = a0;
    A[(size_t)h * 512 + 256 + tid] = a1;
}

// Wfc1[h, n*256+e] = sum_d A[h, n*128+d]*v_w[n*128+d, e]; cols 1024..1087 = fc1_w[h,512+l]
__global__ __launch_bounds__(256) void prep_wfc1(const float* __restrict__ A,
                                                 const float* __restrict__ v_w,
                                                 const float* __restrict__ v_b,
                                                 const float* __restrict__ fc1_w,
                                                 const float* __restrict__ out_b,
                                                 const float* __restrict__ fc1_b,
                                                 _Float16* __restrict__ Wfc1,
                                                 float* __restrict__ biasf) {
    const int h = blockIdx.x, tid = threadIdx.x;
    #pragma unroll
    for (int g = 0; g < 4; ++g) {
        float acc = 0.f;
        for (int dd = 0; dd < 128; ++dd)
            acc += A[h * 512 + g * 128 + dd] * v_w[(g * 128 + dd) * 256 + tid];
        Wfc1[(size_t)h * 1088 + g * 256 + tid] = (_Float16)acc;
    }
    if (tid < 64)
        Wfc1[(size_t)h * 1088 + 1024 + tid] = (_Float16)fc1_w[h * 576 + 512 + tid];
    float ps = A[h * 512 + tid] * v_b[tid] + A[h * 512 + 256 + tid] * v_b[256 + tid]
             + fc1_w[h * 576 + tid] * out_b[tid] + fc1_w[h * 576 + 256 + tid] * out_b[256 + tid];
    #pragma unroll
    for (int off = 32; off; off >>= 1) ps += __shfl_down(ps, off);
    __shared__ float red[4];
    if ((tid & 63) == 0) red[tid >> 6] = ps;
    __syncthreads();
    if (tid == 0) biasf[h] = red[0] + red[1] + red[2] + red[3] + fc1_b[h];
}

// LSTM weights: concat [wih|whh] -> fp16 [2048 x 1024], rows reordered to h*4+gate.
__global__ __launch_bounds__(256) void prep_lstm(const float* __restrict__ wih,
                                                 const float* __restrict__ whh,
                                                 const float* __restrict__ bih,
                                                 const float* __restrict__ bhh,
                                                 _Float16* __restrict__ Wc,
                                                 float* __restrict__ bc) {
    int idx = blockIdx.x * 256 + threadIdx.x;  // 2,097,152
    int rp = idx >> 10, cc = idx & 1023;
    int h = rp >> 2, g = rp & 3;
    int rsrc = g * 512 + h;
    float v = (cc < 512) ? wih[(size_t)rsrc * 512 + cc] : whh[(size_t)rsrc * 512 + cc - 512];
    Wc[idx] = (_Float16)v;
    if (idx < 2048) {
        int h2 = idx >> 2, g2 = idx & 3;
        bc[idx] = bih[g2 * 512 + h2] + bhh[g2 * 512 + h2];
    }
}

// fc2 weights -> straight fp16 casts (no transpose; GEMMs run X @ W^T).
__global__ __launch_bounds__(256) void prep_fc2c(const float* __restrict__ aw,
                                                 const float* __restrict__ bw,
                                                 const float* __restrict__ cw,
                                                 _Float16* __restrict__ a16,
                                                 _Float16* __restrict__ b16,
                                                 _Float16* __restrict__ c16) {
    int i = blockIdx.x * 256 + threadIdx.x;
    if (i < 131072) a16[i] = (_Float16)aw[i];
    else if (i < 163840) b16[i - 131072] = (_Float16)bw[i - 131072];
    else if (i < 164096) c16[i - 163840] = (_Float16)cw[i - 163840];
}

// ---------------------------------------------------------------- GEMM core (reg double-buffered)
// Computes out = X @ W^T on a BMxBN tile. W row-major [N,K].
// acc layout per 16x16 tile: row=(lane>>4)*4+r, col=lane&15.
template <int NTHR, int BM, int BN, int BK, int WM, int WN>
DEVI void gemm_core_db(char* smem_raw, const _Float16* __restrict__ X, int ldx,
                       const _Float16* __restrict__ W, int ldw, int K,
                       int bm0, int bn0, f32x4* acc) {
    constexpr int LDT = BK + 8;
    _Float16* Xs = (_Float16*)smem_raw;
    _Float16* Ws = Xs + BM * LDT;
    const int tid = threadIdx.x, wave = tid >> 6, lane = tid & 63;
    constexpr int WROWS = BM / WM;
    static_assert(WROWS * (BN / WN) == NTHR / 64, "wave grid mismatch");
    const int wm = wave % WROWS, wn = wave / WROWS;
    constexpr int MT = WM / 16, NT = WN / 16;
    const int q = lane >> 4, m15 = lane & 15;
    constexpr int CPR = BK / 8;
    constexpr int XCH = BM * CPR, WCH = BN * CPR;
    constexpr int XPT = (XCH + NTHR - 1) / NTHR;
    constexpr int WPT = (WCH + NTHR - 1) / NTHR;
    uint4 xr[XPT], wr[WPT];
    auto ldregs = [&](int k0) {
        #pragma unroll
        for (int c = 0; c < XPT; ++c) {
            int cc = tid + c * NTHR;
            if ((XCH % NTHR) == 0 || cc < XCH) {
                int row = cc / CPR, col = (cc % CPR) * 8;
                xr[c] = *(const uint4*)&X[(size_t)(bm0 + row) * ldx + k0 + col];
            }
        }
        #pragma unroll
        for (int c = 0; c < WPT; ++c) {
            int cc = tid + c * NTHR;
            if ((WCH % NTHR) == 0 || cc < WCH) {
                int row = cc / CPR, col = (cc % CPR) * 8;
                wr[c] = *(const uint4*)&W[(size_t)(bn0 + row) * ldw + k0 + col];
            }
        }
    };
    ldregs(0);
    for (int k0 = 0; k0 < K; k0 += BK) {
        #pragma unroll
        for (int c = 0; c < XPT; ++c) {
            int cc = tid + c * NTHR;
            if ((XCH % NTHR) == 0 || cc < XCH) {
                int row = cc / CPR, col = (cc % CPR) * 8;
                *(uint4*)&Xs[row * LDT + col] = xr[c];
            }
        }
        #pragma unroll
        for (int c = 0; c < WPT; ++c) {
            int cc = tid + c * NTHR;
            if ((WCH % NTHR) == 0 || cc < WCH) {
                int row = cc / CPR, col = (cc % CPR) * 8;
                *(uint4*)&Ws[row * LDT + col] = wr[c];
            }
        }
        __syncthreads();
        if (k0 + BK < K) ldregs(k0 + BK);   // overlap next-tile loads with MFMA phase
        #pragma unroll
        for (int kk = 0; kk < BK / 32; ++kk) {
            f16x8 af[MT], bf[NT];
            #pragma unroll
            for (int i = 0; i < MT; ++i)
                af[i] = *(const f16x8*)&Xs[(wm * WM + i * 16 + m15) * LDT + kk * 32 + q * 8];
            #pragma unroll
            for (int j = 0; j < NT; ++j)
                bf[j] = *(const f16x8*)&Ws[(wn * WN + j * 16 + m15) * LDT + kk * 32 + q * 8];
            #pragma unroll
            for (int i = 0; i < MT; ++i)
                #pragma unroll
                for (int j = 0; j < NT; ++j)
                    acc[i * NT + j] = __builtin_amdgcn_mfma_f32_16x16x32_f16(af[i], bf[j], acc[i * NT + j], 0, 0, 0);
        }
        __syncthreads();
    }
}

template <int BM, int BN, int WM, int WN, int ACT>
DEVI void epi_plain(const f32x4* acc, const float* __restrict__ bias,
                    _Float16* __restrict__ out, int ldo, int bm0, int bn0) {
    const int tid = threadIdx.x, wave = tid >> 6, lane = tid & 63;
    constexpr int WROWS = BM / WM;
    const int wm = wave % WROWS, wn = wave / WROWS;
    constexpr int MT = WM / 16, NT = WN / 16;
    const int q = lane >> 4, m15 = lane & 15;
    #pragma unroll
    for (int i = 0; i < MT; ++i) {
        #pragma unroll
        for (int j = 0; j < NT; ++j) {
            int col = bn0 + wn * WN + j * 16 + m15;
            float bv = bias[col];
            #pragma unroll
            for (int r = 0; r < 4; ++r) {
                int rowg = bm0 + wm * WM + i * 16 + q * 4 + r;
                float v = acc[i * NT + j][r] + bv;
                if (ACT == 1) v = lrelu(v);
                out[(size_t)rowg * ldo + col] = (_Float16)v;
            }
        }
    }
}

// ---------------------------------------------------------------- global barrier
// Two-level arrival: 16 group counters (one cache line each) -> world counter ->
// generation flag. Release side: __threadfence (agent) flushes this XCD's L2.
// Spin side: relaxed agent-scope polls (no L2-invalidate per poll), single
// acquire fence after the flag is observed. Safety valve converts a pathological
// deadlock into a wrong answer instead of a hang.
DEVI void gbar(unsigned* bars, int grp, unsigned want) {
    __syncthreads();
    if (threadIdx.x == 0) {
        __threadfence();
        unsigned a = __hip_atomic_fetch_add(&bars[grp * 32], 1u,
                                            __ATOMIC_ACQ_REL, __HIP_MEMORY_SCOPE_AGENT);
        if (a == 15u) {
            __hip_atomic_store(&bars[grp * 32], 0u, __ATOMIC_RELAXED, __HIP_MEMORY_SCOPE_AGENT);
            unsigned b = __hip_atomic_fetch_add(&bars[512], 1u,
                                                __ATOMIC_ACQ_REL, __HIP_MEMORY_SCOPE_AGENT);
            if (b == 15u) {
                __hip_atomic_store(&bars[512], 0u, __ATOMIC_RELAXED, __HIP_MEMORY_SCOPE_AGENT);
                __hip_atomic_store(&bars[544], want, __ATOMIC_RELEASE, __HIP_MEMORY_SCOPE_AGENT);
            }
        }
        unsigned spins = 0;
        while (__hip_atomic_load(&bars[544], __ATOMIC_RELAXED, __HIP_MEMORY_SCOPE_AGENT) < want) {
            __builtin_amdgcn_s_sleep(2);
            if (++spins > (1u << 16)) break;   // ~25ms safety valve
        }
        __threadfence();
    }
    __syncthreads();
}

// ---------------------------------------------------------------- attention phase
// One block handles 4 batches sequentially; encH for the next batch is
// prefetched into registers while the current batch computes (hides L3/HBM lat).
// LDS: encs 51200 | gs 8192 | sc 2048 | wsm 2048 | part 8192 = 71680 B.
DEVI void attn_phase(char* smem, const _Float16* __restrict__ G,
                     const _Float16* __restrict__ encH, const float* __restrict__ z,
                     _Float16* __restrict__ eb, int b0, int t) {
    _Float16* encs = (_Float16*)smem;                  // [100][256]
    _Float16* gs   = (_Float16*)(smem + 51200);        // [4][1024]
    float* sc      = (float*)(smem + 59392);           // [4][128]
    float* wsm     = (float*)(smem + 61440);           // [4][128]
    f32x4* part    = (f32x4*)(smem + 63488);           // [8][64]
    const int tid = threadIdx.x;
    uint4 r[7];
    auto ldenc = [&](int b) {
        const uint4* src = (const uint4*)(encH + (size_t)b * (SEQ * ENC));
        #pragma unroll
        for (int i = 0; i < 6; ++i) r[i] = src[tid + i * 512];
        if (tid < 128) r[6] = src[tid + 3072];
    };
    ldenc(b0);
    {   // all 4 G rows -> LDS (1 uint4 per thread)
        int row = tid >> 7, idx = tid & 127;
        *(uint4*)&gs[row * 1024 + idx * 8] = *(const uint4*)&G[(size_t)(b0 + row) * 1024 + idx * 8];
    }
    for (int i = 0; i < 4; ++i) {
        {   // staged regs -> LDS
            uint4* dst = (uint4*)encs;
            #pragma unroll
            for (int k = 0; k < 6; ++k) dst[tid + k * 512] = r[k];
            if (tid < 128) dst[tid + 3072] = r[6];
        }
        __syncthreads();
        if (i < 3) ldenc(b0 + i + 1);     // prefetch next batch under compute
        const int b = b0 + i;
        {   // scores: 32 groups of 16 lanes; group = (head n, s-offset)
            const int grpq = tid >> 4, l16 = tid & 15, n = grpq & 3, soff = grpq >> 2;
            const f16x8 g0 = *(const f16x8*)&gs[i * 1024 + n * 256 + l16 * 8];
            const f16x8 g1 = *(const f16x8*)&gs[i * 1024 + n * 256 + 128 + l16 * 8];
            for (int it = 0; it < 13; ++it) {
                int s = it * 8 + soff;
                if (s < SEQ) {
                    const f16x8 e0 = *(const f16x8*)&encs[s * ENC + l16 * 8];
                    const f16x8 e1 = *(const f16x8*)&encs[s * ENC + 128 + l16 * 8];
                    float p = 0.f;
                    #pragma unroll
                    for (int j = 0; j < 8; ++j)
                        p += (float)e0[j] * (float)g0[j] + (float)e1[j] * (float)g1[j];
                    p += __shfl_xor(p, 1); p += __shfl_xor(p, 2);
                    p += __shfl_xor(p, 4); p += __shfl_xor(p, 8);
                    if (l16 == 0) sc[n * 128 + s] = p;
                }
            }
        }
        __syncthreads();
        const int wv = tid >> 6, ln = tid & 63;
        if (wv < 4) {   // softmax per head
            float v0 = sc[wv * 128 + ln];
            float v1 = (ln < SEQ - 64) ? sc[wv * 128 + 64 + ln] : -1e30f;
            float m = fmaxf(v0, v1);
            #pragma unroll
            for (int off = 32; off; off >>= 1) m = fmaxf(m, __shfl_xor(m, off));
            float e0 = __expf(v0 - m);
            float e1 = (ln < SEQ - 64) ? __expf(v1 - m) : 0.f;
            float ss = e0 + e1;
            #pragma unroll
            for (int off = 32; off; off >>= 1) ss += __shfl_xor(ss, off);
            float inv = 1.f / ss;
            wsm[wv * 128 + ln] = e0 * inv;
            if (ln < SEQ - 64) wsm[wv * 128 + 64 + ln] = e1 * inv;
        }
        __syncthreads();
        {   // weighted sum: all 8 waves, s-range split in halves per head
            const int n = wv & 3, half = wv >> 2;
            float a0 = 0.f, a1 = 0.f, a2 = 0.f, a3 = 0.f;
            const int sBeg = half * 50, sEnd = sBeg + 50;
            #pragma unroll 5
            for (int s = sBeg; s < sEnd; ++s) {
                f16x4 e4 = *(const f16x4*)&encs[s * ENC + ln * 4];
                float w = wsm[n * 128 + s];
                a0 += w * (float)e4.x; a1 += w * (float)e4.y;
                a2 += w * (float)e4.z; a3 += w * (float)e4.w;
            }
            f32x4 pv; pv[0] = a0; pv[1] = a1; pv[2] = a2; pv[3] = a3;
            part[wv * 64 + ln] = pv;
        }
        __syncthreads();
        if (wv < 4) {
            f32x4 p0 = part[wv * 64 + ln], p1 = part[(wv + 4) * 64 + ln];
            f16x4 o;
            o.x = (_Float16)(p0[0] + p1[0]); o.y = (_Float16)(p0[1] + p1[1]);
            o.z = (_Float16)(p0[2] + p1[2]); o.w = (_Float16)(p0[3] + p1[3]);
            *(f16x4*)&eb[(size_t)b * 1088 + wv * 256 + ln * 4] = o;
        } else if (wv == 4) {
            eb[(size_t)b * 1088 + 1024 + ln] = (_Float16)z[((size_t)b * TT + t) * LAT + ln];
        }
        __syncthreads();   // protect encs/part before next batch overwrites
    }
}

// ---------------------------------------------------------------- LSTM phase
// Gates GEMM (64x128 tile, rows h*4+gate) + fused elementwise. c-state lives in
// cr[4] registers (block->tile mapping is static across all 30 steps).
// hn is written ONLY to hA (disjoint from this phase's GEMM inputs -> race-free).
DEVI void lstm_phase(char* smem, const _Float16* __restrict__ X,
                     const _Float16* __restrict__ W, const float* __restrict__ bias,
                     float (&cr)[4], _Float16* __restrict__ hA, int ldA,
                     int bm0, int bn0) {
    f32x4 acc[4] = {};
    gemm_core_db<512, 64, 128, 64, 32, 32>(smem, X, 1024, W, 1024, 1024, bm0, bn0, acc);
    float* accs = (float*)smem;   // [64][132]
    const int tid = threadIdx.x, wave = tid >> 6, lane = tid & 63;
    const int wm = wave & 1, wn = wave >> 1, q = lane >> 4, m15 = lane & 15;
    #pragma unroll
    for (int i = 0; i < 2; ++i) {
        #pragma unroll
        for (int j = 0; j < 2; ++j) {
            int cl = wn * 32 + j * 16 + m15;
            float bv = bias[bn0 + cl];
            #pragma unroll
            for (int r = 0; r < 4; ++r) {
                int rl = wm * 32 + i * 16 + q * 4 + r;
                accs[rl * 132 + cl] = acc[i * 2 + j][r] + bv;
            }
        }
    }
    __syncthreads();
    #pragma unroll
    for (int u = 0; u < 4; ++u) {
        int pair = tid + u * 512;         // 64 rows x 32 h
        int bl = pair >> 5, hl = pair & 31;
        float4 g4 = *(const float4*)&accs[bl * 132 + hl * 4];  // i,f,g,o
        int h = (bn0 >> 2) + hl, gb = bm0 + bl;
        float cn = sigm(g4.y) * cr[u] + sigm(g4.x) * tanh_f(g4.z);
        cr[u] = cn;
        hA[(size_t)gb * ldA + h] = (_Float16)(sigm(g4.w) * tanh_f(cn));
    }
}

// ---------------------------------------------------------------- fc2 chain (512 thr, 16 batches)
DEVI void fc2_512(char* smem, const _Float16* __restrict__ h2n,
                  const _Float16* __restrict__ Wa, const float* __restrict__ ab,
                  const _Float16* __restrict__ Wb, const float* __restrict__ bb,
                  const _Float16* __restrict__ Wc, const float* __restrict__ cb,
                  float* __restrict__ out, int b0, int t) {
    _Float16* h2s = (_Float16*)smem;       // [16][520]
    _Float16* y1s = h2s + 16 * 520;        // [16][264]
    _Float16* y2s = y1s + 16 * 264;        // [16][136]
    const int tid = threadIdx.x, wave = tid >> 6, lane = tid & 63;
    const int q = lane >> 4, m15 = lane & 15;
    #pragma unroll
    for (int c = 0; c < 2; ++c) {
        int cc = tid + c * 512, row = cc >> 6, col = (cc & 63) * 8;
        *(uint4*)&h2s[row * 520 + col] = *(const uint4*)&h2n[(size_t)(b0 + row) * 512 + col];
    }
    __syncthreads();
    {   // y1[16,256] = lrelu(h2 @ Wa^T + ab); wave handles 32 cols
        f32x4 acc[2] = {};
        #pragma unroll 4
        for (int kk = 0; kk < 16; ++kk) {
            f16x8 af = *(const f16x8*)&h2s[m15 * 520 + kk * 32 + q * 8];
            #pragma unroll
            for (int j = 0; j < 2; ++j) {
                int n = wave * 32 + j * 16 + m15;
                f16x8 bf = *(const f16x8*)&Wa[(size_t)n * 512 + kk * 32 + q * 8];
                acc[j] = __builtin_amdgcn_mfma_f32_16x16x32_f16(af, bf, acc[j], 0, 0, 0);
            }
        }
        #pragma unroll
        for (int j = 0; j < 2; ++j) {
            int col = wave * 32 + j * 16 + m15;
            float bv = ab[col];
            #pragma unroll
            for (int r = 0; r < 4; ++r)
                y1s[(q * 4 + r) * 264 + col] = (_Float16)lrelu(acc[j][r] + bv);
        }
    }
    __syncthreads();
    {   // y2[16,128] = lrelu(y1 @ Wb^T + bb); wave handles 16 cols
        f32x4 acc[1] = {};
        #pragma unroll
        for (int kk = 0; kk < 8; ++kk) {
            f16x8 af = *(const f16x8*)&y1s[m15 * 264 + kk * 32 + q * 8];
            int n = wave * 16 + m15;
            f16x8 bf = *(const f16x8*)&Wb[(size_t)n * 256 + kk * 32 + q * 8];
            acc[0] = __builtin_amdgcn_mfma_f32_16x16x32_f16(af, bf, acc[0], 0, 0, 0);
        }
        int col = wave * 16 + m15;
        float bv = bb[col];
        #pragma unroll
        for (int r = 0; r < 4; ++r)
            y2s[(q * 4 + r) * 136 + col] = (_Float16)lrelu(acc[0][r] + bv);
    }
    __syncthreads();
    if (tid < 32) {   // y3: 16 batches x 2 outs, tanh
        int r = tid >> 1, o = tid & 1;
        float acc = cb[o];
        #pragma unroll 8
        for (int k = 0; k < 128; ++k)
            acc += (float)Wc[o * 128 + k] * (float)y2s[r * 136 + k];
        out[((size_t)(b0 + r) * TT + t) * 2 + o] = tanhf(acc);
    }
}

// ---------------------------------------------------------------- persistent decoder
struct DecP {
    const _Float16* encH;
    const float* z;
    _Float16* eb;
    const _Float16* Wfc1;  const float* biasf;
    const _Float16* L1W;   const float* L1b;
    const _Float16* L2W;   const float* L2b;
    const _Float16* C_h;   const float* d_f;  const _Float16* d_h;
    const _Float16* fa;    const float* fab;
    const _Float16* fb;    const float* fbb;
    const _Float16* fcw;   const float* fcb;
    _Float16* xh1;  _Float16* xh2;  _Float16* h2n;  _Float16* G;
    float* out;
    unsigned* bars;
};

__global__ __launch_bounds__(512, 2) void decoder(DecP p) {
    __shared__ __align__(16) char smem[71680];
    const int blk = blockIdx.x, tid = threadIdx.x;
    const int grp = blk >> 4, sub = blk & 15;   // 16 groups x 16 blocks; group owns 64 batches
    const int b0a = blk * 4;                    // this block's 4 attn batches
    const int bm0 = grp * 64;                   // GEMM row tile
    float c1r[4] = {0.f, 0.f, 0.f, 0.f}, c2r[4] = {0.f, 0.f, 0.f, 0.f};
    unsigned want = 0;
    {   // G(0) = broadcast d (q-proj of h2=0); block writes only its own rows.
        unsigned int v = *(const unsigned int*)&p.d_h[tid * 2];
        #pragma unroll
        for (int i = 0; i < 4; ++i)
            *(unsigned int*)&p.G[(size_t)(b0a + i) * 1024 + tid * 2] = v;
    }
    __syncthreads();
    for (int t = 0; t < TT; ++t) {
        // A: attention (4 batches, enc reg-prefetch double buffer)
        attn_phase(smem, p.G, p.encH, p.z, p.eb, b0a, t);
        gbar(p.bars, grp, ++want);
        // B: fc1 = lrelu(eb @ Wfc1^T + biasf) -> xh1[:, :512]
        {
            f32x4 acc[1] = {};
            gemm_core_db<512, 64, 32, 64, 16, 16>(smem, p.eb, 1088, p.Wfc1, 1088, 1088,
                                                  bm0, sub * 32, acc);
            epi_plain<64, 32, 16, 16, 1>(acc, p.biasf, p.xh1, 1024, bm0, sub * 32);
        }
        gbar(p.bars, grp, ++want);
        // C: LSTM1, X = [fc1out | h1(t-1)]; h1(t) -> xh2[:, :512] only (race-free)
        lstm_phase(smem, p.xh1, p.L1W, p.L1b, c1r, p.xh2, 1024, bm0, sub * 128);
        gbar(p.bars, grp, ++want);
        // D: LSTM2, X = [h1(t) | h2(t-1)]; h2(t) -> h2n only (race-free)
        lstm_phase(smem, p.xh2, p.L2W, p.L2b, c2r, p.h2n, 512, bm0, sub * 128);
        gbar(p.bars, grp, ++want);
        // E: h-state copies for next step, q-projection GEMM, fc2 output
        {
            int row = tid >> 3, c4 = (tid & 7) * 4;
            size_t ro = (size_t)(bm0 + row);
            f16x4 h1v = *(const f16x4*)&p.xh2[ro * 1024 + sub * 32 + c4];
            *(f16x4*)&p.xh1[ro * 1024 + 512 + sub * 32 + c4] = h1v;   // h1 -> lstm1 input
            f16x4 h2v = *(const f16x4*)&p.h2n[ro * 512 + sub * 32 + c4];
            *(f16x4*)&p.xh2[ro * 1024 + 512 + sub * 32 + c4] = h2v;   // h2 -> lstm2 input
        }
        {
            f32x4 acc[2] = {};
            gemm_core_db<512, 64, 64, 64, 16, 32>(smem, p.h2n, 512, p.C_h, 512, 512,
                                                  bm0, sub * 64, acc);
            epi_plain<64, 64, 16, 32, 0>(acc, p.d_f, p.G, 1024, bm0, sub * 64);
            if (sub < 4)
                fc2_512(smem, p.h2n, p.fa, p.fab, p.fb, p.fbb, p.fcw, p.fcb,
                        p.out, bm0 + sub * 16, t);
        }
        if (t < TT - 1) gbar(p.bars, grp, ++want);
    }
}

// ---------------------------------------------------------------- launch
extern "C" void kernel_launch(void* const* d_in, const int* in_sizes, int n_in,
                              void* d_out, int out_size, void* d_ws, size_t ws_size,
                              hipStream_t stream) {
    const float* encoded = (const float*)d_in[0];
    const float* z       = (const float*)d_in[1];
    const float* q_w     = (const float*)d_in[2];
    const float* k_w     = (const float*)d_in[3];
    const float* v_w     = (const float*)d_in[4];
    const float* q_b     = (const float*)d_in[5];
    // d_in[6] (k_b): softmax-invariant — dropped exactly.
    const float* v_b     = (const float*)d_in[7];
    const float* out_w   = (const float*)d_in[8];
    const float* out_b   = (const float*)d_in[9];
    const float* fc1_w   = (const float*)d_in[10];
    const float* fc1_b   = (const float*)d_in[11];
    const float* l1_wih  = (const float*)d_in[12];
    const float* l1_whh  = (const float*)d_in[13];
    const float* l1_bih  = (const float*)d_in[14];
    const float* l1_bhh  = (const float*)d_in[15];
    const float* l2_wih  = (const float*)d_in[16];
    const float* l2_whh  = (const float*)d_in[17];
    const float* l2_bih  = (const float*)d_in[18];
    const float* l2_bhh  = (const float*)d_in[19];
    const float* fc2a_w  = (const float*)d_in[20];
    const float* fc2a_b  = (const float*)d_in[21];
    const float* fc2b_w  = (const float*)d_in[22];
    const float* fc2b_b  = (const float*)d_in[23];
    const float* fc2c_w  = (const float*)d_in[24];
    const float* fc2c_b  = (const float*)d_in[25];
    float* out = (float*)d_out;

    char* p = (char*)d_ws;
    auto take = [&](size_t bytes) { char* r = p; p += (bytes + 255) & ~(size_t)255; return r; };
    _Float16* encH  = (_Float16*)take(52428800);   // [1024,100,256] fp16
    _Float16* C_h   = (_Float16*)take(1048576);    // [1024,512]
    _Float16* Wfc1  = (_Float16*)take(1114112);    // [512,1088]
    _Float16* L1W   = (_Float16*)take(4194304);    // [2048,1024] rows h*4+g
    _Float16* L2W   = (_Float16*)take(4194304);
    _Float16* fc2a16= (_Float16*)take(262144);     // [256,512]
    _Float16* fc2b16= (_Float16*)take(65536);      // [128,256]
    _Float16* fc2c16= (_Float16*)take(512);        // [2,128]
    _Float16* eb    = (_Float16*)take(2228224);    // [1024,1088]
    _Float16* h2n   = (_Float16*)take(1048576);    // [1024,512]  h2(t)
    char* zreg = p;                                // ---- zero region (4 MB + 4 KB) ----
    _Float16* xh1 = (_Float16*)take(2097152);      // [1024,1024] = [fc1out | h1]
    _Float16* xh2 = (_Float16*)take(2097152);      // [1024,1024] = [h1 | h2]
    unsigned* bars = (unsigned*)take(4096);        // barrier counters + gen
    // ---- end zero region ----
    _Float16* G   = (_Float16*)take(2097152);      // [1024,1024] (init in-kernel)
    float* A      = (float*)take(1048576);
    float* d_f    = (float*)take(4096);
    _Float16* d_h = (_Float16*)take(2048);
    float* biasf  = (float*)take(2048);
    float* L1b    = (float*)take(8192);
    float* L2b    = (float*)take(8192);
    (void)in_sizes; (void)n_in; (void)out_size; (void)ws_size;

    zero_ws<<<1025, 256, 0, stream>>>((uint4*)zreg);   // xh1+xh2+bars = 1025*4096 B
    conv_enc<<<25600, 256, 0, stream>>>((const float4*)encoded, (f16x4*)encH);
    prep_qk<<<1024, 256, 0, stream>>>(k_w, q_w, q_b, C_h, d_f, d_h);
    prep_A<<<512, 256, 0, stream>>>(fc1_w, out_w, A);
    prep_wfc1<<<512, 256, 0, stream>>>(A, v_w, v_b, fc1_w, out_b, fc1_b, Wfc1, biasf);
    prep_lstm<<<8192, 256, 0, stream>>>(l1_wih, l1_whh, l1_bih, l1_bhh, L1W, L1b);
    prep_lstm<<<8192, 256, 0, stream>>>(l2_wih, l2_whh, l2_bih, l2_bhh, L2W, L2b);
    prep_fc2c<<<641, 256, 0, stream>>>(fc2a_w, fc2b_w, fc2c_w, fc2a16, fc2b16, fc2c16);

    DecP dp;
    dp.encH = encH; dp.z = z; dp.eb = eb;
    dp.Wfc1 = Wfc1; dp.biasf = biasf;
    dp.L1W = L1W; dp.L1b = L1b; dp.L2W = L2W; dp.L2b = L2b;
    dp.C_h = C_h; dp.d_f = d_f; dp.d_h = d_h;
    dp.fa = fc2a16; dp.fab = fc2a_b; dp.fb = fc2b16; dp.fbb = fc2b_b;
    dp.fcw = fc2c16; dp.fcb = fc2c_b;
    dp.xh1 = xh1; dp.xh2 = xh2; dp.h2n = h2n; dp.G = G;
    dp.out = out; dp.bars = bars;
    void* params[] = { &dp };
    // Cooperative launch guarantees co-residency for the in-kernel barrier.
    // 256 blocks x 512 thr, 71680 B LDS -> >=1 block/CU, always satisfiable.
    if (hipLaunchCooperativeKernel((const void*)decoder, dim3(256), dim3(512),
                                   params, 0, stream) != hipSuccess) {
        // Fallback: plain launch. grid(256) <= #CUs and <=2 blocks/CU capacity
        // => all workgroups resident at dispatch; barrier remains safe.
        decoder<<<256, 512, 0, stream>>>(dp);
    }
}

// Round 2
// 4583.636 us; speedup vs baseline: 1.4660x; 1.4660x over previous
//
#include <hip/hip_runtime.h>

// Generator_78683800862785: attention+LSTM decoder, BS=1024, T=30.
// R2: persistent kernel, coherence protocol rebuilt.
//  - R1 regression diagnosed: device-wide 2-level barrier + __threadfence
//    (agent acquire => L2 invalidate) refetched ~85MB/step from L3 (FETCH
//    2.55GB) and cost ~15us/barrier. Everything was latency-bound idle.
//  - R2: per-GROUP barriers (deps are contained in 16-block/64-batch groups);
//    NO cache-invalidating fences at all. Cross-block activations (eb, xh1,
//    xh2, h2n, G) go through sc0/sc1 (system-coherent, L1/L2-bypass) inline-asm
//    loads/stores -- produced/consumed at the memory-side coherence point.
//    Barrier = vmcnt(0) drain + release atomic arrive + relaxed poll.
//    Weights/encH stay L2-cached across the whole kernel (never invalidated).
//  - LSTM c-state in registers across all 30 steps (unchanged from R1).

#define DEVI __device__ __forceinline__

typedef _Float16 f16x8 __attribute__((ext_vector_type(8)));
typedef _Float16 f16x4 __attribute__((ext_vector_type(4)));
typedef float    f32x4 __attribute__((ext_vector_type(4)));

#define BSZ 1024
#define SEQ 100
#define ENC 256
#define HID 512
#define LAT 64
#define TT  30

// ---------------------------------------------------------------- utilities
DEVI float lrelu(float v) { return v >= 0.f ? v : 0.2f * v; }
DEVI float sigm(float x)  { return 1.f / (1.f + __expf(-x)); }
DEVI float tanh_f(float x){ return 1.f - 2.f / (1.f + __expf(2.f * x)); }

// ---- system-coherent (L1/L2-bypass) access helpers. Loads are issued async;
// caller MUST call wait_vm0() before consuming outputs. Stores fire-and-forget;
// drained by wait_vm0() in gbar before arrival.
DEVI void wait_vm0() { asm volatile("s_waitcnt vmcnt(0)" ::: "memory"); }
DEVI void ld_sc_b128(uint4& d, const void* p) {
    asm volatile("global_load_dwordx4 %0, %1, off sc0 sc1" : "=&v"(d) : "v"(p) : "memory");
}
DEVI void ld_sc_b64(uint2& d, const void* p) {
    asm volatile("global_load_dwordx2 %0, %1, off sc0 sc1" : "=&v"(d) : "v"(p) : "memory");
}
DEVI void st_sc_b128(void* p, uint4 v) {
    asm volatile("global_store_dwordx4 %0, %1, off sc0 sc1" :: "v"(p), "v"(v) : "memory");
}
DEVI void st_sc_b64(void* p, uint2 v) {
    asm volatile("global_store_dwordx2 %0, %1, off sc0 sc1" :: "v"(p), "v"(v) : "memory");
}
DEVI void st_sc_b32(void* p, unsigned v) {
    asm volatile("global_store_dword %0, %1, off sc0 sc1" :: "v"(p), "v"(v) : "memory");
}
DEVI void st_sc_b16(void* p, unsigned v) {
    asm volatile("global_store_short %0, %1, off sc0 sc1" :: "v"(p), "v"(v) : "memory");
}
DEVI unsigned h16bits(_Float16 h) { return (unsigned)__builtin_bit_cast(unsigned short, h); }

// ---------------------------------------------------------------- setup kernels
__global__ __launch_bounds__(256) void zero_ws(uint4* __restrict__ p) {
    uint4 z; z.x = z.y = z.z = z.w = 0u;
    p[(size_t)blockIdx.x * 256 + threadIdx.x] = z;
}

__global__ __launch_bounds__(256) void conv_enc(const float4* __restrict__ src,
                                                f16x4* __restrict__ dst) {
    size_t i = (size_t)blockIdx.x * 256 + threadIdx.x;
    float4 v = src[i];
    f16x4 h;
    h.x = (_Float16)v.x; h.y = (_Float16)v.y; h.z = (_Float16)v.z; h.w = (_Float16)v.w;
    dst[i] = h;
}

// C[ne,h] = scale * sum_d k_w[n*128+d, e] * q_w[n*128+d, h]   (fp16 out)
// d[ne]   = scale * sum_d k_w[n*128+d, e] * q_b[n*128+d]
__global__ __launch_bounds__(256) void prep_qk(const float* __restrict__ k_w,
                                               const float* __restrict__ q_w,
                                               const float* __restrict__ q_b,
                                               _Float16* __restrict__ C_h,
                                               float* __restrict__ d_f,
                                               _Float16* __restrict__ d_h) {
    const int ne = blockIdx.x, n = ne >> 8, e = ne & 255, tid = threadIdx.x;
    const float scale = 0.08838834764831845f;  // 1/sqrt(128)
    float a0 = 0.f, a1 = 0.f;
    for (int dd = 0; dd < 128; ++dd) {
        float kv = k_w[(n * 128 + dd) * 256 + e];
        a0 += kv * q_w[(n * 128 + dd) * 512 + tid];
        a1 += kv * q_w[(n * 128 + dd) * 512 + 256 + tid];
    }
    C_h[(size_t)ne * 512 + tid]       = (_Float16)(scale * a0);
    C_h[(size_t)ne * 512 + 256 + tid] = (_Float16)(scale * a1);
    float pq = (tid < 128) ? k_w[(n * 128 + tid) * 256 + e] * q_b[n * 128 + tid] : 0.f;
    #pragma unroll
    for (int off = 32; off; off >>= 1) pq += __shfl_down(pq, off);
    __shared__ float red[4];
    if ((tid & 63) == 0) red[tid >> 6] = pq;
    __syncthreads();
    if (tid == 0) {
        float s = scale * (red[0] + red[1] + red[2] + red[3]);
        d_f[ne] = s; d_h[ne] = (_Float16)s;
    }
}

// A[h,k] = sum_m fc1_w[h, m] * out_w[m, k]
__global__ __launch_bounds__(256) void prep_A(const float* __restrict__ fc1_w,
                                              const float* __restrict__ out_w,
                                              float* __restrict__ A) {
    const int h = blockIdx.x, tid = threadIdx.x;
    float a0 = 0.f, a1 = 0.f;
    for (int m = 0; m < 512; ++m) {
        float fv = fc1_w[h * 576 + m];
        a0 += fv * out_w[m * 512 + tid];
        a1 += fv * out_w[m * 512 + 256 + tid];
    }
    A[(size_t)h * 512 + tid]       = a0;
    A[(size_t)h * 512 + 256 + tid] = a1;
}

// Wfc1[h, n*256+e] = sum_d A[h, n*128+d]*v_w[n*128+d, e]; cols 1024..1087 = fc1_w[h,512+l]
__global__ __launch_bounds__(256) void prep_wfc1(const float* __restrict__ A,
                                                 const float* __restrict__ v_w,
                                                 const float* __restrict__ v_b,
                                                 const float* __restrict__ fc1_w,
                                                 const float* __restrict__ out_b,
                                                 const float* __restrict__ fc1_b,
                                                 _Float16* __restrict__ Wfc1,
                                                 float* __restrict__ biasf) {
    const int h = blockIdx.x, tid = threadIdx.x;
    #pragma unroll
    for (int g = 0; g < 4; ++g) {
        float acc = 0.f;
        for (int dd = 0; dd < 128; ++dd)
            acc += A[h * 512 + g * 128 + dd] * v_w[(g * 128 + dd) * 256 + tid];
        Wfc1[(size_t)h * 1088 + g * 256 + tid] = (_Float16)acc;
    }
    if (tid < 64)
        Wfc1[(size_t)h * 1088 + 1024 + tid] = (_Float16)fc1_w[h * 576 + 512 + tid];
    float ps = A[h * 512 + tid] * v_b[tid] + A[h * 512 + 256 + tid] * v_b[256 + tid]
             + fc1_w[h * 576 + tid] * out_b[tid] + fc1_w[h * 576 + 256 + tid] * out_b[256 + tid];
    #pragma unroll
    for (int off = 32; off; off >>= 1) ps += __shfl_down(ps, off);
    __shared__ float red[4];
    if ((tid & 63) == 0) red[tid >> 6] = ps;
    __syncthreads();
    if (tid == 0) biasf[h] = red[0] + red[1] + red[2] + red[3] + fc1_b[h];
}

// LSTM weights: concat [wih|whh] -> fp16 [2048 x 1024], rows reordered to h*4+gate.
__global__ __launch_bounds__(256) void prep_lstm(const float* __restrict__ wih,
                                                 const float* __restrict__ whh,
                                                 const float* __restrict__ bih,
                                                 const float* __restrict__ bhh,
                                                 _Float16* __restrict__ Wc,
                                                 float* __restrict__ bc) {
    int idx = blockIdx.x * 256 + threadIdx.x;  // 2,097,152
    int rp = idx >> 10, cc = idx & 1023;
    int h = rp >> 2, g = rp & 3;
    int rsrc = g * 512 + h;
    float v = (cc < 512) ? wih[(size_t)rsrc * 512 + cc] : whh[(size_t)rsrc * 512 + cc - 512];
    Wc[idx] = (_Float16)v;
    if (idx < 2048) {
        int h2 = idx >> 2, g2 = idx & 3;
        bc[idx] = bih[g2 * 512 + h2] + bhh[g2 * 512 + h2];
    }
}

// fc2 weights -> straight fp16 casts (no transpose; GEMMs run X @ W^T).
__global__ __launch_bounds__(256) void prep_fc2c(const float* __restrict__ aw,
                                                 const float* __restrict__ bw,
                                                 const float* __restrict__ cw,
                                                 _Float16* __restrict__ a16,
                                                 _Float16* __restrict__ b16,
                                                 _Float16* __restrict__ c16) {
    int i = blockIdx.x * 256 + threadIdx.x;
    if (i < 131072) a16[i] = (_Float16)aw[i];
    else if (i < 163840) b16[i - 131072] = (_Float16)bw[i - 131072];
    else if (i < 164096) c16[i - 163840] = (_Float16)cw[i - 163840];
}

// ---------------------------------------------------------------- GEMM core (reg double-buffered)
// Computes out = X @ W^T on a BMxBN tile. W row-major [N,K].
// BYPX: X loads are system-coherent bypass (activation tensors); W stays cached.
// acc layout per 16x16 tile: row=(lane>>4)*4+r, col=lane&15.
template <int NTHR, int BM, int BN, int BK, int WM, int WN, bool BYPX>
DEVI void gemm_core_db(char* smem_raw, const _Float16* __restrict__ X, int ldx,
                       const _Float16* __restrict__ W, int ldw, int K,
                       int bm0, int bn0, f32x4* acc) {
    constexpr int LDT = BK + 8;
    _Float16* Xs = (_Float16*)smem_raw;
    _Float16* Ws = Xs + BM * LDT;
    const int tid = threadIdx.x, wave = tid >> 6, lane = tid & 63;
    constexpr int WROWS = BM / WM;
    static_assert(WROWS * (BN / WN) == NTHR / 64, "wave grid mismatch");
    const int wm = wave % WROWS, wn = wave / WROWS;
    constexpr int MT = WM / 16, NT = WN / 16;
    const int q = lane >> 4, m15 = lane & 15;
    constexpr int CPR = BK / 8;
    constexpr int XCH = BM * CPR, WCH = BN * CPR;
    constexpr int XPT = (XCH + NTHR - 1) / NTHR;
    constexpr int WPT = (WCH + NTHR - 1) / NTHR;
    uint4 xr[XPT], wr[WPT];
    auto ldregs = [&](int k0) {
        #pragma unroll
        for (int c = 0; c < XPT; ++c) {
            int cc = tid + c * NTHR;
            if ((XCH % NTHR) == 0 || cc < XCH) {
                int row = cc / CPR, col = (cc % CPR) * 8;
                const void* px = &X[(size_t)(bm0 + row) * ldx + k0 + col];
                if (BYPX) ld_sc_b128(xr[c], px);
                else      xr[c] = *(const uint4*)px;
            }
        }
        #pragma unroll
        for (int c = 0; c < WPT; ++c) {
            int cc = tid + c * NTHR;
            if ((WCH % NTHR) == 0 || cc < WCH) {
                int row = cc / CPR, col = (cc % CPR) * 8;
                wr[c] = *(const uint4*)&W[(size_t)(bn0 + row) * ldw + k0 + col];
            }
        }
    };
    ldregs(0);
    for (int k0 = 0; k0 < K; k0 += BK) {
        if (BYPX) wait_vm0();   // asm loads of this tile are now complete
        #pragma unroll
        for (int c = 0; c < XPT; ++c) {
            int cc = tid + c * NTHR;
            if ((XCH % NTHR) == 0 || cc < XCH) {
                int row = cc / CPR, col = (cc % CPR) * 8;
                *(uint4*)&Xs[row * LDT + col] = xr[c];
            }
        }
        #pragma unroll
        for (int c = 0; c < WPT; ++c) {
            int cc = tid + c * NTHR;
            if ((WCH % NTHR) == 0 || cc < WCH) {
                int row = cc / CPR, col = (cc % CPR) * 8;
                *(uint4*)&Ws[row * LDT + col] = wr[c];
            }
        }
        __syncthreads();
        if (k0 + BK < K) ldregs(k0 + BK);   // overlap next-tile loads with MFMA phase
        #pragma unroll
        for (int kk = 0; kk < BK / 32; ++kk) {
            f16x8 af[MT], bf[NT];
            #pragma unroll
            for (int i = 0; i < MT; ++i)
                af[i] = *(const f16x8*)&Xs[(wm * WM + i * 16 + m15) * LDT + kk * 32 + q * 8];
            #pragma unroll
            for (int j = 0; j < NT; ++j)
                bf[j] = *(const f16x8*)&Ws[(wn * WN + j * 16 + m15) * LDT + kk * 32 + q * 8];
            #pragma unroll
            for (int i = 0; i < MT; ++i)
                #pragma unroll
                for (int j = 0; j < NT; ++j)
                    acc[i * NT + j] = __builtin_amdgcn_mfma_f32_16x16x32_f16(af[i], bf[j], acc[i * NT + j], 0, 0, 0);
        }
        __syncthreads();
    }
}

// Epilogue: bias + optional lrelu, bypass stores (outputs are activations).
template <int BM, int BN, int WM, int WN, int ACT>
DEVI void epi_plain(const f32x4* acc, const float* __restrict__ bias,
                    _Float16* __restrict__ out, int ldo, int bm0, int bn0) {
    const int tid = threadIdx.x, wave = tid >> 6, lane = tid & 63;
    constexpr int WROWS = BM / WM;
    const int wm = wave % WROWS, wn = wave / WROWS;
    constexpr int MT = WM / 16, NT = WN / 16;
    const int q = lane >> 4, m15 = lane & 15;
    #pragma unroll
    for (int i = 0; i < MT; ++i) {
        #pragma unroll
        for (int j = 0; j < NT; ++j) {
            int col = bn0 + wn * WN + j * 16 + m15;
            float bv = bias[col];
            #pragma unroll
            for (int r = 0; r < 4; ++r) {
                int rowg = bm0 + wm * WM + i * 16 + q * 4 + r;
                float v = acc[i * NT + j][r] + bv;
                if (ACT == 1) v = lrelu(v);
                st_sc_b16(&out[(size_t)rowg * ldo + col], h16bits((_Float16)v));
            }
        }
    }
}

// ---------------------------------------------------------------- group barrier
// 16 blocks of one group. All activation data moved via sc0/sc1 bypass ops, so
// no cache maintenance needed: drain stores (vmcnt 0), release-arrive on the
// group's counter line, last arriver publishes generation flag; relaxed polls.
// L2 is never invalidated => weights stay cached for the whole kernel.
DEVI void gbar(unsigned* bars, int grp, unsigned want) {
    wait_vm0();                     // every thread drains its bypass stores
    __syncthreads();
    if (threadIdx.x == 0) {
        unsigned* cnt  = &bars[grp * 64];
        unsigned* flag = &bars[grp * 64 + 32];
        unsigned a = __hip_atomic_fetch_add(cnt, 1u, __ATOMIC_RELEASE, __HIP_MEMORY_SCOPE_AGENT);
        if (a == 15u) {
            __hip_atomic_store(cnt, 0u, __ATOMIC_RELAXED, __HIP_MEMORY_SCOPE_AGENT);
            __hip_atomic_store(flag, want, __ATOMIC_RELEASE, __HIP_MEMORY_SCOPE_AGENT);
        }
        unsigned spins = 0;
        while (__hip_atomic_load(flag, __ATOMIC_RELAXED, __HIP_MEMORY_SCOPE_AGENT) < want) {
            __builtin_amdgcn_s_sleep(1);
            if (++spins > (1u << 16)) break;   // safety valve
        }
        asm volatile("" ::: "memory");
    }
    __syncthreads();
}

// ---------------------------------------------------------------- attention phase
// One block handles 4 batches sequentially; encH (cached) for the next batch is
// prefetched into registers while the current batch computes. G is read via
// bypass loads (written by phase E of the previous step).
// LDS: encs 51200 | gs 8192 | sc 2048 | wsm 2048 | part 8192 = 71680 B.
DEVI void attn_phase(char* smem, const _Float16* __restrict__ G,
                     const _Float16* __restrict__ encH, const float* __restrict__ z,
                     _Float16* __restrict__ eb, int b0, int t) {
    _Float16* encs = (_Float16*)smem;                  // [100][256]
    _Float16* gs   = (_Float16*)(smem + 51200);        // [4][1024]
    float* sc      = (float*)(smem + 59392);           // [4][128]
    float* wsm     = (float*)(smem + 61440);           // [4][128]
    f32x4* part    = (f32x4*)(smem + 63488);           // [8][64]
    const int tid = threadIdx.x;
    uint4 r[7];
    auto ldenc = [&](int b) {
        const uint4* src = (const uint4*)(encH + (size_t)b * (SEQ * ENC));
        #pragma unroll
        for (int i = 0; i < 6; ++i) r[i] = src[tid + i * 512];
        if (tid < 128) r[6] = src[tid + 3072];
    };
    ldenc(b0);
    uint4 gv;
    {   // all 4 G rows (bypass: produced by other blocks last phase)
        int row = tid >> 7, idx = tid & 127;
        ld_sc_b128(gv, &G[(size_t)(b0 + row) * 1024 + idx * 8]);
    }
    wait_vm0();
    {
        int row = tid >> 7, idx = tid & 127;
        *(uint4*)&gs[row * 1024 + idx * 8] = gv;
    }
    for (int i = 0; i < 4; ++i) {
        {   // staged regs -> LDS
            uint4* dst = (uint4*)encs;
            #pragma unroll
            for (int k = 0; k < 6; ++k) dst[tid + k * 512] = r[k];
            if (tid < 128) dst[tid + 3072] = r[6];
        }
        __syncthreads();
        if (i < 3) ldenc(b0 + i + 1);     // prefetch next batch under compute
        const int b = b0 + i;
        {   // scores: 32 groups of 16 lanes; group = (head n, s-offset)
            const int grpq = tid >> 4, l16 = tid & 15, n = grpq & 3, soff = grpq >> 2;
            const f16x8 g0 = *(const f16x8*)&gs[i * 1024 + n * 256 + l16 * 8];
            const f16x8 g1 = *(const f16x8*)&gs[i * 1024 + n * 256 + 128 + l16 * 8];
            for (int it = 0; it < 13; ++it) {
                int s = it * 8 + soff;
                if (s < SEQ) {
                    const f16x8 e0 = *(const f16x8*)&encs[s * ENC + l16 * 8];
                    const f16x8 e1 = *(const f16x8*)&encs[s * ENC + 128 + l16 * 8];
                    float p = 0.f;
                    #pragma unroll
                    for (int j = 0; j < 8; ++j)
                        p += (float)e0[j] * (float)g0[j] + (float)e1[j] * (float)g1[j];
                    p += __shfl_xor(p, 1); p += __shfl_xor(p, 2);
                    p += __shfl_xor(p, 4); p += __shfl_xor(p, 8);
                    if (l16 == 0) sc[n * 128 + s] = p;
                }
            }
        }
        __syncthreads();
        const int wv = tid >> 6, ln = tid & 63;
        if (wv < 4) {   // softmax per head
            float v0 = sc[wv * 128 + ln];
            float v1 = (ln < SEQ - 64) ? sc[wv * 128 + 64 + ln] : -1e30f;
            float m = fmaxf(v0, v1);
            #pragma unroll
            for (int off = 32; off; off >>= 1) m = fmaxf(m, __shfl_xor(m, off));
            float e0 = __expf(v0 - m);
            float e1 = (ln < SEQ - 64) ? __expf(v1 - m) : 0.f;
            float ss = e0 + e1;
            #pragma unroll
            for (int off = 32; off; off >>= 1) ss += __shfl_xor(ss, off);
            float inv = 1.f / ss;
            wsm[wv * 128 + ln] = e0 * inv;
            if (ln < SEQ - 64) wsm[wv * 128 + 64 + ln] = e1 * inv;
        }
        __syncthreads();
        {   // weighted sum: all 8 waves, s-range split in halves per head
            const int n = wv & 3, half = wv >> 2;
            float a0 = 0.f, a1 = 0.f, a2 = 0.f, a3 = 0.f;
            const int sBeg = half * 50, sEnd = sBeg + 50;
            #pragma unroll 5
            for (int s = sBeg; s < sEnd; ++s) {
                f16x4 e4 = *(const f16x4*)&encs[s * ENC + ln * 4];
                float w = wsm[n * 128 + s];
                a0 += w * (float)e4.x; a1 += w * (float)e4.y;
                a2 += w * (float)e4.z; a3 += w * (float)e4.w;
            }
            f32x4 pv; pv[0] = a0; pv[1] = a1; pv[2] = a2; pv[3] = a3;
            part[wv * 64 + ln] = pv;
        }
        __syncthreads();
        if (wv < 4) {
            f32x4 p0 = part[wv * 64 + ln], p1 = part[(wv + 4) * 64 + ln];
            f16x4 o;
            o.x = (_Float16)(p0[0] + p1[0]); o.y = (_Float16)(p0[1] + p1[1]);
            o.z = (_Float16)(p0[2] + p1[2]); o.w = (_Float16)(p0[3] + p1[3]);
            st_sc_b64(&eb[(size_t)b * 1088 + wv * 256 + ln * 4], __builtin_bit_cast(uint2, o));
        } else if (wv == 4) {
            st_sc_b16(&eb[(size_t)b * 1088 + 1024 + ln],
                      h16bits((_Float16)z[((size_t)b * TT + t) * LAT + ln]));
        }
        __syncthreads();   // protect encs/part before next batch overwrites
    }
}

// ---------------------------------------------------------------- LSTM phase
// Gates GEMM (64x128 tile, rows h*4+gate) + fused elementwise. c-state lives in
// cr[4] registers. hn goes ONLY to hA via bypass store (disjoint from this
// phase's GEMM inputs -> race-free).
DEVI void lstm_phase(char* smem, const _Float16* __restrict__ X,
                     const _Float16* __restrict__ W, const float* __restrict__ bias,
                     float (&cr)[4], _Float16* __restrict__ hA, int ldA,
                     int bm0, int bn0) {
    f32x4 acc[4] = {};
    gemm_core_db<512, 64, 128, 64, 32, 32, true>(smem, X, 1024, W, 1024, 1024, bm0, bn0, acc);
    float* accs = (float*)smem;   // [64][132]
    const int tid = threadIdx.x, wave = tid >> 6, lane = tid & 63;
    const int wm = wave & 1, wn = wave >> 1, q = lane >> 4, m15 = lane & 15;
    #pragma unroll
    for (int i = 0; i < 2; ++i) {
        #pragma unroll
        for (int j = 0; j < 2; ++j) {
            int cl = wn * 32 + j * 16 + m15;
            float bv = bias[bn0 + cl];
            #pragma unroll
            for (int r = 0; r < 4; ++r) {
                int rl = wm * 32 + i * 16 + q * 4 + r;
                accs[rl * 132 + cl] = acc[i * 2 + j][r] + bv;
            }
        }
    }
    __syncthreads();
    #pragma unroll
    for (int u = 0; u < 4; ++u) {
        int pair = tid + u * 512;         // 64 rows x 32 h
        int bl = pair >> 5, hl = pair & 31;
        float4 g4 = *(const float4*)&accs[bl * 132 + hl * 4];  // i,f,g,o
        int h = (bn0 >> 2) + hl, gb = bm0 + bl;
        float cn = sigm(g4.y) * cr[u] + sigm(g4.x) * tanh_f(g4.z);
        cr[u] = cn;
        st_sc_b16(&hA[(size_t)gb * ldA + h], h16bits((_Float16)(sigm(g4.w) * tanh_f(cn))));
    }
}

// ---------------------------------------------------------------- fc2 chain (512 thr, 16 batches)
DEVI void fc2_512(char* smem, const _Float16* __restrict__ h2n,
                  const _Float16* __restrict__ Wa, const float* __restrict__ ab,
                  const _Float16* __restrict__ Wb, const float* __restrict__ bb,
                  const _Float16* __restrict__ Wc, const float* __restrict__ cb,
                  float* __restrict__ out, int b0, int t) {
    _Float16* h2s = (_Float16*)smem;       // [16][520]
    _Float16* y1s = h2s + 16 * 520;        // [16][264]
    _Float16* y2s = y1s + 16 * 264;        // [16][136]
    const int tid = threadIdx.x, wave = tid >> 6, lane = tid & 63;
    const int q = lane >> 4, m15 = lane & 15;
    uint4 hv[2];
    #pragma unroll
    for (int c = 0; c < 2; ++c) {
        int cc = tid + c * 512, row = cc >> 6, col = (cc & 63) * 8;
        ld_sc_b128(hv[c], &h2n[(size_t)(b0 + row) * 512 + col]);
    }
    wait_vm0();
    #pragma unroll
    for (int c = 0; c < 2; ++c) {
        int cc = tid + c * 512, row = cc >> 6, col = (cc & 63) * 8;
        *(uint4*)&h2s[row * 520 + col] = hv[c];
    }
    __syncthreads();
    {   // y1[16,256] = lrelu(h2 @ Wa^T + ab); wave handles 32 cols
        f32x4 acc[2] = {};
        #pragma unroll 4
        for (int kk = 0; kk < 16; ++kk) {
            f16x8 af = *(const f16x8*)&h2s[m15 * 520 + kk * 32 + q * 8];
            #pragma unroll
            for (int j = 0; j < 2; ++j) {
                int n = wave * 32 + j * 16 + m15;
                f16x8 bf = *(const f16x8*)&Wa[(size_t)n * 512 + kk * 32 + q * 8];
                acc[j] = __builtin_amdgcn_mfma_f32_16x16x32_f16(af, bf, acc[j], 0, 0, 0);
            }
        }
        #pragma unroll
        for (int j = 0; j < 2; ++j) {
            int col = wave * 32 + j * 16 + m15;
            float bv = ab[col];
            #pragma unroll
            for (int r = 0; r < 4; ++r)
                y1s[(q * 4 + r) * 264 + col] = (_Float16)lrelu(acc[j][r] + bv);
        }
    }
    __syncthreads();
    {   // y2[16,128] = lrelu(y1 @ Wb^T + bb); wave handles 16 cols
        f32x4 acc[1] = {};
        #pragma unroll
        for (int kk = 0; kk < 8; ++kk) {
            f16x8 af = *(const f16x8*)&y1s[m15 * 264 + kk * 32 + q * 8];
            int n = wave * 16 + m15;
            f16x8 bf = *(const f16x8*)&Wb[(size_t)n * 256 + kk * 32 + q * 8];
            acc[0] = __builtin_amdgcn_mfma_f32_16x16x32_f16(af, bf, acc[0], 0, 0, 0);
        }
        int col = wave * 16 + m15;
        float bv = bb[col];
        #pragma unroll
        for (int r = 0; r < 4; ++r)
            y2s[(q * 4 + r) * 136 + col] = (_Float16)lrelu(acc[0][r] + bv);
    }
    __syncthreads();
    if (tid < 32) {   // y3: 16 batches x 2 outs, tanh; out is cached (host-read only)
        int r = tid >> 1, o = tid & 1;
        float acc = cb[o];
        #pragma unroll 8
        for (int k = 0; k < 128; ++k)
            acc += (float)Wc[o * 128 + k] * (float)y2s[r * 136 + k];
        out[((size_t)(b0 + r) * TT + t) * 2 + o] = tanhf(acc);
    }
}

// ---------------------------------------------------------------- persistent decoder
struct DecP {
    const _Float16* encH;
    const float* z;
    _Float16* eb;
    const _Float16* Wfc1;  const float* biasf;
    const _Float16* L1W;   const float* L1b;
    const _Float16* L2W;   const float* L2b;
    const _Float16* C_h;   const float* d_f;  const _Float16* d_h;
    const _Float16* fa;    const float* fab;
    const _Float16* fb;    const float* fbb;
    const _Float16* fcw;   const float* fcb;
    _Float16* xh1;  _Float16* xh2;  _Float16* h2n;  _Float16* G;
    float* out;
    unsigned* bars;
};

__global__ __launch_bounds__(512, 2) void decoder(DecP p) {
    __shared__ __align__(16) char smem[71680];
    const int blk = blockIdx.x, tid = threadIdx.x;
    const int grp = blk >> 4, sub = blk & 15;   // 16 groups x 16 blocks; group owns 64 batches
    const int b0a = blk * 4;                    // this block's 4 attn batches
    const int bm0 = grp * 64;                   // GEMM row tile
    float c1r[4] = {0.f, 0.f, 0.f, 0.f}, c2r[4] = {0.f, 0.f, 0.f, 0.f};
    unsigned want = 0;
    {   // G(0) = broadcast d (q-proj of h2=0); bypass stores (read via bypass later).
        unsigned v = *(const unsigned*)&p.d_h[tid * 2];
        #pragma unroll
        for (int i = 0; i < 4; ++i)
            st_sc_b32(&p.G[(size_t)(b0a + i) * 1024 + tid * 2], v);
    }
    wait_vm0();
    __syncthreads();
    for (int t = 0; t < TT; ++t) {
        // A: attention (4 batches, enc reg-prefetch double buffer)
        attn_phase(smem, p.G, p.encH, p.z, p.eb, b0a, t);
        gbar(p.bars, grp, ++want);
        // B: fc1 = lrelu(eb @ Wfc1^T + biasf) -> xh1[:, :512]
        {
            f32x4 acc[1] = {};
            gemm_core_db<512, 64, 32, 64, 16, 16, true>(smem, p.eb, 1088, p.Wfc1, 1088, 1088,
                                                        bm0, sub * 32, acc);
            epi_plain<64, 32, 16, 16, 1>(acc, p.biasf, p.xh1, 1024, bm0, sub * 32);
        }
        gbar(p.bars, grp, ++want);
        // C: LSTM1, X = [fc1out | h1(t-1)]; h1(t) -> xh2[:, :512] only (race-free)
        lstm_phase(smem, p.xh1, p.L1W, p.L1b, c1r, p.xh2, 1024, bm0, sub * 128);
        gbar(p.bars, grp, ++want);
        // D: LSTM2, X = [h1(t) | h2(t-1)]; h2(t) -> h2n only (race-free)
        lstm_phase(smem, p.xh2, p.L2W, p.L2b, c2r, p.h2n, 512, bm0, sub * 128);
        gbar(p.bars, grp, ++want);
        // E: h-state copies for next step, q-projection GEMM, fc2 output
        {
            int row = tid >> 3, c4 = (tid & 7) * 4;
            size_t ro = (size_t)(bm0 + row);
            uint2 h1v, h2v;
            ld_sc_b64(h1v, &p.xh2[ro * 1024 + sub * 32 + c4]);
            ld_sc_b64(h2v, &p.h2n[ro * 512 + sub * 32 + c4]);
            wait_vm0();
            st_sc_b64(&p.xh1[ro * 1024 + 512 + sub * 32 + c4], h1v);   // h1 -> lstm1 input
            st_sc_b64(&p.xh2[ro * 1024 + 512 + sub * 32 + c4], h2v);   // h2 -> lstm2 input
        }
        {
            f32x4 acc[2] = {};
            gemm_core_db<512, 64, 64, 64, 16, 32, true>(smem, p.h2n, 512, p.C_h, 512, 512,
                                                        bm0, sub * 64, acc);
            epi_plain<64, 64, 16, 32, 0>(acc, p.d_f, p.G, 1024, bm0, sub * 64);
            if (sub < 4)
                fc2_512(smem, p.h2n, p.fa, p.fab, p.fb, p.fbb, p.fcw, p.fcb,
                        p.out, bm0 + sub * 16, t);
        }
        if (t < TT - 1) gbar(p.bars, grp, ++want);
    }
}

// ---------------------------------------------------------------- launch
extern "C" void kernel_launch(void* const* d_in, const int* in_sizes, int n_in,
                              void* d_out, int out_size, void* d_ws, size_t ws_size,
                              hipStream_t stream) {
    const float* encoded = (const float*)d_in[0];
    const float* z       = (const float*)d_in[1];
    const float* q_w     = (const float*)d_in[2];
    const float* k_w     = (const float*)d_in[3];
    const float* v_w     = (const float*)d_in[4];
    const float* q_b     = (const float*)d_in[5];
    // d_in[6] (k_b): softmax-invariant — dropped exactly.
    const float* v_b     = (const float*)d_in[7];
    const float* out_w   = (const float*)d_in[8];
    const float* out_b   = (const float*)d_in[9];
    const float* fc1_w   = (const float*)d_in[10];
    const float* fc1_b   = (const float*)d_in[11];
    const float* l1_wih  = (const float*)d_in[12];
    const float* l1_whh  = (const float*)d_in[13];
    const float* l1_bih  = (const float*)d_in[14];
    const float* l1_bhh  = (const float*)d_in[15];
    const float* l2_wih  = (const float*)d_in[16];
    const float* l2_whh  = (const float*)d_in[17];
    const float* l2_bih  = (const float*)d_in[18];
    const float* l2_bhh  = (const float*)d_in[19];
    const float* fc2a_w  = (const float*)d_in[20];
    const float* fc2a_b  = (const float*)d_in[21];
    const float* fc2b_w  = (const float*)d_in[22];
    const float* fc2b_b  = (const float*)d_in[23];
    const float* fc2c_w  = (const float*)d_in[24];
    const float* fc2c_b  = (const float*)d_in[25];
    float* out = (float*)d_out;

    char* p = (char*)d_ws;
    auto take = [&](size_t bytes) { char* r = p; p += (bytes + 255) & ~(size_t)255; return r; };
    _Float16* encH  = (_Float16*)take(52428800);   // [1024,100,256] fp16
    _Float16* C_h   = (_Float16*)take(1048576);    // [1024,512]
    _Float16* Wfc1  = (_Float16*)take(1114112);    // [512,1088]
    _Float16* L1W   = (_Float16*)take(4194304);    // [2048,1024] rows h*4+g
    _Float16* L2W   = (_Float16*)take(4194304);
    _Float16* fc2a16= (_Float16*)take(262144);     // [256,512]
    _Float16* fc2b16= (_Float16*)take(65536);      // [128,256]
    _Float16* fc2c16= (_Float16*)take(512);        // [2,128]
    _Float16* eb    = (_Float16*)take(2228224);    // [1024,1088]
    _Float16* h2n   = (_Float16*)take(1048576);    // [1024,512]  h2(t)
    char* zreg = p;                                // ---- zero region (4 MB + 4 KB) ----
    _Float16* xh1 = (_Float16*)take(2097152);      // [1024,1024] = [fc1out | h1]
    _Float16* xh2 = (_Float16*)take(2097152);      // [1024,1024] = [h1 | h2]
    unsigned* bars = (unsigned*)take(4096);        // per-group barrier counters/flags
    // ---- end zero region ----
    _Float16* G   = (_Float16*)take(2097152);      // [1024,1024] (init in-kernel)
    float* A      = (float*)take(1048576);
    float* d_f    = (float*)take(4096);
    _Float16* d_h = (_Float16*)take(2048);
    float* biasf  = (float*)take(2048);
    float* L1b    = (float*)take(8192);
    float* L2b    = (float*)take(8192);
    (void)in_sizes; (void)n_in; (void)out_size; (void)ws_size;

    zero_ws<<<1025, 256, 0, stream>>>((uint4*)zreg);   // xh1+xh2+bars = 1025*4096 B
    conv_enc<<<25600, 256, 0, stream>>>((const float4*)encoded, (f16x4*)encH);
    prep_qk<<<1024, 256, 0, stream>>>(k_w, q_w, q_b, C_h, d_f, d_h);
    prep_A<<<512, 256, 0, stream>>>(fc1_w, out_w, A);
    prep_wfc1<<<512, 256, 0, stream>>>(A, v_w, v_b, fc1_w, out_b, fc1_b, Wfc1, biasf);
    prep_lstm<<<8192, 256, 0, stream>>>(l1_wih, l1_whh, l1_bih, l1_bhh, L1W, L1b);
    prep_lstm<<<8192, 256, 0, stream>>>(l2_wih, l2_whh, l2_bih, l2_bhh, L2W, L2b);
    prep_fc2c<<<641, 256, 0, stream>>>(fc2a_w, fc2b_w, fc2c_w, fc2a16, fc2b16, fc2c16);

    DecP dp;
    dp.encH = encH; dp.z = z; dp.eb = eb;
    dp.Wfc1 = Wfc1; dp.biasf = biasf;
    dp.L1W = L1W; dp.L1b = L1b; dp.L2W = L2W; dp.L2b = L2b;
    dp.C_h = C_h; dp.d_f = d_f; dp.d_h = d_h;
    dp.fa = fc2a16; dp.fab = fc2a_b; dp.fb = fc2b16; dp.fbb = fc2b_b;
    dp.fcw = fc2c16; dp.fcb = fc2c_b;
    dp.xh1 = xh1; dp.xh2 = xh2; dp.h2n = h2n; dp.G = G;
    dp.out = out; dp.bars = bars;
    void* params[] = { &dp };
    // Cooperative launch guarantees co-residency for the in-kernel barrier.
    // 256 blocks x 512 thr, 71680 B LDS -> >=1 block/CU, always satisfiable.
    if (hipLaunchCooperativeKernel((const void*)decoder, dim3(256), dim3(512),
                                   params, 0, stream) != hipSuccess) {
        // Fallback: plain launch. grid(256) <= #CUs => all workgroups resident
        // at dispatch; per-group barrier remains safe.
        decoder<<<256, 512, 0, stream>>>(dp);
    }
}

// Round 4
// 3308.978 us; speedup vs baseline: 2.0307x; 1.3852x over previous
//
#include <hip/hip_runtime.h>

// Generator_78683800862785: attention+LSTM decoder, BS=1024, T=30.
// R4 = R3 with the inline-asm constraint fix. R3's "indirect register input"
// compile error: passing uint4& lvalues (array elements) as asm "v" operands
// put them in scratch. Fix: bypass helpers return/take ext_vector_type values
// (u32x4/u32x2) so asm outputs are SSA temps (always registers).
// R3 plan (unchanged): all activation stores are 16B packed f16x8 system
// stores (epilogues stage in LDS then repack; LSTM gate-ew 8-h-per-thread with
// cr[8] register c-state; attn output repacked); LSTM+q-proj GEMMs BK=128;
// __launch_bounds__(512,1); last step skips q-proj + h-copies.
// Coherence model from R2: per-group barriers, sc0sc1 bypass for cross-block
// activations, weights/encH through normal cached path (L2 never invalidated).

#define DEVI __device__ __forceinline__

typedef _Float16 f16x8 __attribute__((ext_vector_type(8)));
typedef _Float16 f16x4 __attribute__((ext_vector_type(4)));
typedef float    f32x4 __attribute__((ext_vector_type(4)));
typedef unsigned u32x4 __attribute__((ext_vector_type(4)));
typedef unsigned u32x2 __attribute__((ext_vector_type(2)));

#define BSZ 1024
#define SEQ 100
#define ENC 256
#define HID 512
#define LAT 64
#define TT  30

// ---------------------------------------------------------------- utilities
DEVI float lrelu(float v) { return v >= 0.f ? v : 0.2f * v; }
DEVI float sigm(float x)  { return 1.f / (1.f + __expf(-x)); }
DEVI float tanh_f(float x){ return 1.f - 2.f / (1.f + __expf(2.f * x)); }

// ---- system-coherent (cache-bypass) access helpers. Loads are issued async;
// caller MUST call wait_vm0() before consuming results. Stores fire-and-forget;
// drained by wait_vm0() in gbar before arrival. Value-typed (ext_vector) so
// asm operands are always registers.
DEVI void wait_vm0() { asm volatile("s_waitcnt vmcnt(0)" ::: "memory"); }
DEVI u32x4 ld_sc_b128(const void* p) {
    u32x4 d;
    asm volatile("global_load_dwordx4 %0, %1, off sc0 sc1" : "=v"(d) : "v"(p) : "memory");
    return d;
}
DEVI void st_sc_b128(void* p, u32x4 v) {
    asm volatile("global_store_dwordx4 %0, %1, off sc0 sc1" :: "v"(p), "v"(v) : "memory");
}
DEVI void st_sc_b64(void* p, u32x2 v) {
    asm volatile("global_store_dwordx2 %0, %1, off sc0 sc1" :: "v"(p), "v"(v) : "memory");
}

// ---------------------------------------------------------------- setup kernels
__global__ __launch_bounds__(256) void zero_ws(uint4* __restrict__ p) {
    uint4 z; z.x = z.y = z.z = z.w = 0u;
    p[(size_t)blockIdx.x * 256 + threadIdx.x] = z;
}

__global__ __launch_bounds__(256) void conv_enc(const float4* __restrict__ src,
                                                f16x4* __restrict__ dst) {
    size_t i = (size_t)blockIdx.x * 256 + threadIdx.x;
    float4 v = src[i];
    f16x4 h;
    h.x = (_Float16)v.x; h.y = (_Float16)v.y; h.z = (_Float16)v.z; h.w = (_Float16)v.w;
    dst[i] = h;
}

// C[ne,h] = scale * sum_d k_w[n*128+d, e] * q_w[n*128+d, h]   (fp16 out)
// d[ne]   = scale * sum_d k_w[n*128+d, e] * q_b[n*128+d]
__global__ __launch_bounds__(256) void prep_qk(const float* __restrict__ k_w,
                                               const float* __restrict__ q_w,
                                               const float* __restrict__ q_b,
                                               _Float16* __restrict__ C_h,
                                               float* __restrict__ d_f,
                                               _Float16* __restrict__ d_h) {
    const int ne = blockIdx.x, n = ne >> 8, e = ne & 255, tid = threadIdx.x;
    const float scale = 0.08838834764831845f;  // 1/sqrt(128)
    float a0 = 0.f, a1 = 0.f;
    for (int dd = 0; dd < 128; ++dd) {
        float kv = k_w[(n * 128 + dd) * 256 + e];
        a0 += kv * q_w[(n * 128 + dd) * 512 + tid];
        a1 += kv * q_w[(n * 128 + dd) * 512 + 256 + tid];
    }
    C_h[(size_t)ne * 512 + tid]       = (_Float16)(scale * a0);
    C_h[(size_t)ne * 512 + 256 + tid] = (_Float16)(scale * a1);
    float pq = (tid < 128) ? k_w[(n * 128 + tid) * 256 + e] * q_b[n * 128 + tid] : 0.f;
    #pragma unroll
    for (int off = 32; off; off >>= 1) pq += __shfl_down(pq, off);
    __shared__ float red[4];
    if ((tid & 63) == 0) red[tid >> 6] = pq;
    __syncthreads();
    if (tid == 0) {
        float s = scale * (red[0] + red[1] + red[2] + red[3]);
        d_f[ne] = s; d_h[ne] = (_Float16)s;
    }
}

// A[h,k] = sum_m fc1_w[h, m] * out_w[m, k]
__global__ __launch_bounds__(256) void prep_A(const float* __restrict__ fc1_w,
                                              const float* __restrict__ out_w,
                                              float* __restrict__ A) {
    const int h = blockIdx.x, tid = threadIdx.x;
    float a0 = 0.f, a1 = 0.f;
    for (int m = 0; m < 512; ++m) {
        float fv = fc1_w[h * 576 + m];
        a0 += fv * out_w[m * 512 + tid];
        a1 += fv * out_w[m * 512 + 256 + tid];
    }
    A[(size_t)h * 512 + tid]       = a0;
    A[(size_t)h * 512 + 256 + tid] = a1;
}

// Wfc1[h, n*256+e] = sum_d A[h, n*128+d]*v_w[n*128+d, e]; cols 1024..1087 = fc1_w[h,512+l]
__global__ __launch_bounds__(256) void prep_wfc1(const float* __restrict__ A,
                                                 const float* __restrict__ v_w,
                                                 const float* __restrict__ v_b,
                                                 const float* __restrict__ fc1_w,
                                                 const float* __restrict__ out_b,
                                                 const float* __restrict__ fc1_b,
                                                 _Float16* __restrict__ Wfc1,
                                                 float* __restrict__ biasf) {
    const int h = blockIdx.x, tid = threadIdx.x;
    #pragma unroll
    for (int g = 0; g < 4; ++g) {
        float acc = 0.f;
        for (int dd = 0; dd < 128; ++dd)
            acc += A[h * 512 + g * 128 + dd] * v_w[(g * 128 + dd) * 256 + tid];
        Wfc1[(size_t)h * 1088 + g * 256 + tid] = (_Float16)acc;
    }
    if (tid < 64)
        Wfc1[(size_t)h * 1088 + 1024 + tid] = (_Float16)fc1_w[h * 576 + 512 + tid];
    float ps = A[h * 512 + tid] * v_b[tid] + A[h * 512 + 256 + tid] * v_b[256 + tid]
             + fc1_w[h * 576 + tid] * out_b[tid] + fc1_w[h * 576 + 256 + tid] * out_b[256 + tid];
    #pragma unroll
    for (int off = 32; off; off >>= 1) ps += __shfl_down(ps, off);
    __shared__ float red[4];
    if ((tid & 63) == 0) red[tid >> 6] = ps;
    __syncthreads();
    if (tid == 0) biasf[h] = red[0] + red[1] + red[2] + red[3] + fc1_b[h];
}

// LSTM weights: concat [wih|whh] -> fp16 [2048 x 1024], rows reordered to h*4+gate.
__global__ __launch_bounds__(256) void prep_lstm(const float* __restrict__ wih,
                                                 const float* __restrict__ whh,
                                                 const float* __restrict__ bih,
                                                 const float* __restrict__ bhh,
                                                 _Float16* __restrict__ Wc,
                                                 float* __restrict__ bc) {
    int idx = blockIdx.x * 256 + threadIdx.x;  // 2,097,152
    int rp = idx >> 10, cc = idx & 1023;
    int h = rp >> 2, g = rp & 3;
    int rsrc = g * 512 + h;
    float v = (cc < 512) ? wih[(size_t)rsrc * 512 + cc] : whh[(size_t)rsrc * 512 + cc - 512];
    Wc[idx] = (_Float16)v;
    if (idx < 2048) {
        int h2 = idx >> 2, g2 = idx & 3;
        bc[idx] = bih[g2 * 512 + h2] + bhh[g2 * 512 + h2];
    }
}

// fc2 weights -> straight fp16 casts (no transpose; GEMMs run X @ W^T).
__global__ __launch_bounds__(256) void prep_fc2c(const float* __restrict__ aw,
                                                 const float* __restrict__ bw,
                                                 const float* __restrict__ cw,
                                                 _Float16* __restrict__ a16,
                                                 _Float16* __restrict__ b16,
                                                 _Float16* __restrict__ c16) {
    int i = blockIdx.x * 256 + threadIdx.x;
    if (i < 131072) a16[i] = (_Float16)aw[i];
    else if (i < 163840) b16[i - 131072] = (_Float16)bw[i - 131072];
    else if (i < 164096) c16[i - 163840] = (_Float16)cw[i - 163840];
}

// ---------------------------------------------------------------- GEMM core (reg double-buffered)
// Computes out = X @ W^T on a BMxBN tile. W row-major [N,K].
// BYPX: X loads are system-coherent bypass (activation tensors); W stays cached.
// acc layout per 16x16 tile: row=(lane>>4)*4+r, col=lane&15.
template <int NTHR, int BM, int BN, int BK, int WM, int WN, bool BYPX>
DEVI void gemm_core_db(char* smem_raw, const _Float16* __restrict__ X, int ldx,
                       const _Float16* __restrict__ W, int ldw, int K,
                       int bm0, int bn0, f32x4* acc) {
    constexpr int LDT = BK + 8;
    _Float16* Xs = (_Float16*)smem_raw;
    _Float16* Ws = Xs + BM * LDT;
    const int tid = threadIdx.x, wave = tid >> 6, lane = tid & 63;
    constexpr int WROWS = BM / WM;
    static_assert(WROWS * (BN / WN) == NTHR / 64, "wave grid mismatch");
    const int wm = wave % WROWS, wn = wave / WROWS;
    constexpr int MT = WM / 16, NT = WN / 16;
    const int q = lane >> 4, m15 = lane & 15;
    constexpr int CPR = BK / 8;
    constexpr int XCH = BM * CPR, WCH = BN * CPR;
    constexpr int XPT = (XCH + NTHR - 1) / NTHR;
    constexpr int WPT = (WCH + NTHR - 1) / NTHR;
    u32x4 xr[XPT], wr[WPT];
    auto ldregs = [&](int k0) {
        #pragma unroll
        for (int c = 0; c < XPT; ++c) {
            int cc = tid + c * NTHR;
            if ((XCH % NTHR) == 0 || cc < XCH) {
                int row = cc / CPR, col = (cc % CPR) * 8;
                const void* px = &X[(size_t)(bm0 + row) * ldx + k0 + col];
                if (BYPX) xr[c] = ld_sc_b128(px);
                else      xr[c] = *(const u32x4*)px;
            }
        }
        #pragma unroll
        for (int c = 0; c < WPT; ++c) {
            int cc = tid + c * NTHR;
            if ((WCH % NTHR) == 0 || cc < WCH) {
                int row = cc / CPR, col = (cc % CPR) * 8;
                wr[c] = *(const u32x4*)&W[(size_t)(bn0 + row) * ldw + k0 + col];
            }
        }
    };
    ldregs(0);
    for (int k0 = 0; k0 < K; k0 += BK) {
        if (BYPX) wait_vm0();   // asm loads of this tile are now complete
        #pragma unroll
        for (int c = 0; c < XPT; ++c) {
            int cc = tid + c * NTHR;
            if ((XCH % NTHR) == 0 || cc < XCH) {
                int row = cc / CPR, col = (cc % CPR) * 8;
                *(u32x4*)&Xs[row * LDT + col] = xr[c];
            }
        }
        #pragma unroll
        for (int c = 0; c < WPT; ++c) {
            int cc = tid + c * NTHR;
            if ((WCH % NTHR) == 0 || cc < WCH) {
                int row = cc / CPR, col = (cc % CPR) * 8;
                *(u32x4*)&Ws[row * LDT + col] = wr[c];
            }
        }
        __syncthreads();
        if (k0 + BK < K) ldregs(k0 + BK);   // overlap next-tile loads with MFMA phase
        #pragma unroll
        for (int kk = 0; kk < BK / 32; ++kk) {
            f16x8 af[MT], bf[NT];
            #pragma unroll
            for (int i = 0; i < MT; ++i)
                af[i] = *(const f16x8*)&Xs[(wm * WM + i * 16 + m15) * LDT + kk * 32 + q * 8];
            #pragma unroll
            for (int j = 0; j < NT; ++j)
                bf[j] = *(const f16x8*)&Ws[(wn * WN + j * 16 + m15) * LDT + kk * 32 + q * 8];
            #pragma unroll
            for (int i = 0; i < MT; ++i)
                #pragma unroll
                for (int j = 0; j < NT; ++j)
                    acc[i * NT + j] = __builtin_amdgcn_mfma_f32_16x16x32_f16(af[i], bf[j], acc[i * NT + j], 0, 0, 0);
        }
        __syncthreads();
    }
}

// Epilogue: stage tile (bias+act applied) in LDS, then packed 16B bypass stores.
template <int NTHR, int BM, int BN, int WM, int WN, int ACT>
DEVI void epi_staged(char* smem_raw, const f32x4* acc, const float* __restrict__ bias,
                     _Float16* __restrict__ out, int ldo, int bm0, int bn0) {
    constexpr int LDS_ = BN + 4;
    float* accs = (float*)smem_raw;
    const int tid = threadIdx.x, wave = tid >> 6, lane = tid & 63;
    constexpr int WROWS = BM / WM;
    const int wm = wave % WROWS, wn = wave / WROWS;
    constexpr int MT = WM / 16, NT = WN / 16;
    const int q = lane >> 4, m15 = lane & 15;
    #pragma unroll
    for (int i = 0; i < MT; ++i) {
        #pragma unroll
        for (int j = 0; j < NT; ++j) {
            int cl = wn * WN + j * 16 + m15;
            float bv = bias[bn0 + cl];
            #pragma unroll
            for (int r = 0; r < 4; ++r) {
                int rl = wm * WM + i * 16 + q * 4 + r;
                float v = acc[i * NT + j][r] + bv;
                if (ACT == 1) v = lrelu(v);
                accs[rl * LDS_ + cl] = v;
            }
        }
    }
    __syncthreads();
    constexpr int CH = BN / 8, ITEMS = BM * CH;
    #pragma unroll
    for (int base = 0; base < ITEMS; base += NTHR) {
        int idx = base + tid;
        if ((ITEMS % NTHR) == 0 || idx < ITEMS) {
            int row = idx / CH, ch = idx % CH;
            const float* src = &accs[row * LDS_ + ch * 8];
            f16x8 o;
            #pragma unroll
            for (int k = 0; k < 8; ++k) o[k] = (_Float16)src[k];
            st_sc_b128(&out[(size_t)(bm0 + row) * ldo + bn0 + ch * 8],
                       __builtin_bit_cast(u32x4, o));
        }
    }
    __syncthreads();
}

// ---------------------------------------------------------------- group barrier
// 16 blocks of one group. All activation data moved via sc0/sc1 bypass ops, so
// no cache maintenance needed: drain stores (vmcnt 0), release-arrive on the
// group's counter line, last arriver publishes generation flag; relaxed polls.
// L2 is never invalidated => weights/encH stay cached for the whole kernel.
DEVI void gbar(unsigned* bars, int grp, unsigned want) {
    wait_vm0();                     // every thread drains its bypass stores
    __syncthreads();
    if (threadIdx.x == 0) {
        unsigned* cnt  = &bars[grp * 64];
        unsigned* flag = &bars[grp * 64 + 32];
        unsigned a = __hip_atomic_fetch_add(cnt, 1u, __ATOMIC_RELEASE, __HIP_MEMORY_SCOPE_AGENT);
        if (a == 15u) {
            __hip_atomic_store(cnt, 0u, __ATOMIC_RELAXED, __HIP_MEMORY_SCOPE_AGENT);
            __hip_atomic_store(flag, want, __ATOMIC_RELEASE, __HIP_MEMORY_SCOPE_AGENT);
        }
        unsigned spins = 0;
        while (__hip_atomic_load(flag, __ATOMIC_RELAXED, __HIP_MEMORY_SCOPE_AGENT) < want) {
            __builtin_amdgcn_s_sleep(1);
            if (++spins > (1u << 16)) break;   // safety valve
        }
        asm volatile("" ::: "memory");
    }
    __syncthreads();
}

// ---------------------------------------------------------------- attention phase
// One block handles 4 batches sequentially; encH (cached) for the next batch is
// prefetched into registers while the current batch computes. G is read via
// bypass loads (written by phase E of the previous step). Output repacked from
// the part[] LDS buffer into 16B stores.
// LDS: encs 51200 | gs 8192 | sc 2048 | wsm 2048 | part 8192 = 71680 B.
DEVI void attn_phase(char* smem, const _Float16* __restrict__ G,
                     const _Float16* __restrict__ encH, const float* __restrict__ z,
                     _Float16* __restrict__ eb, int b0, int t) {
    _Float16* encs = (_Float16*)smem;                  // [100][256]
    _Float16* gs   = (_Float16*)(smem + 51200);        // [4][1024]
    float* sc      = (float*)(smem + 59392);           // [4][128]
    float* wsm     = (float*)(smem + 61440);           // [4][128]
    f32x4* part    = (f32x4*)(smem + 63488);           // [8][64]
    const int tid = threadIdx.x;
    u32x4 r[7];
    auto ldenc = [&](int b) {
        const u32x4* src = (const u32x4*)(encH + (size_t)b * (SEQ * ENC));
        #pragma unroll
        for (int i = 0; i < 6; ++i) r[i] = src[tid + i * 512];
        if (tid < 128) r[6] = src[tid + 3072];
    };
    ldenc(b0);
    u32x4 gv;
    {   // all 4 G rows (bypass: produced by other blocks last phase)
        int row = tid >> 7, idx = tid & 127;
        gv = ld_sc_b128(&G[(size_t)(b0 + row) * 1024 + idx * 8]);
    }
    wait_vm0();
    {
        int row = tid >> 7, idx = tid & 127;
        *(u32x4*)&gs[row * 1024 + idx * 8] = gv;
    }
    for (int i = 0; i < 4; ++i) {
        {   // staged regs -> LDS
            u32x4* dst = (u32x4*)encs;
            #pragma unroll
            for (int k = 0; k < 6; ++k) dst[tid + k * 512] = r[k];
            if (tid < 128) dst[tid + 3072] = r[6];
        }
        __syncthreads();
        if (i < 3) ldenc(b0 + i + 1);     // prefetch next batch under compute
        const int b = b0 + i;
        {   // scores: 32 groups of 16 lanes; group = (head n, s-offset)
            const int grpq = tid >> 4, l16 = tid & 15, n = grpq & 3, soff = grpq >> 2;
            const f16x8 g0 = *(const f16x8*)&gs[i * 1024 + n * 256 + l16 * 8];
            const f16x8 g1 = *(const f16x8*)&gs[i * 1024 + n * 256 + 128 + l16 * 8];
            for (int it = 0; it < 13; ++it) {
                int s = it * 8 + soff;
                if (s < SEQ) {
                    const f16x8 e0 = *(const f16x8*)&encs[s * ENC + l16 * 8];
                    const f16x8 e1 = *(const f16x8*)&encs[s * ENC + 128 + l16 * 8];
                    float p = 0.f;
                    #pragma unroll
                    for (int j = 0; j < 8; ++j)
                        p += (float)e0[j] * (float)g0[j] + (float)e1[j] * (float)g1[j];
                    p += __shfl_xor(p, 1); p += __shfl_xor(p, 2);
                    p += __shfl_xor(p, 4); p += __shfl_xor(p, 8);
                    if (l16 == 0) sc[n * 128 + s] = p;
                }
            }
        }
        __syncthreads();
        const int wv = tid >> 6, ln = tid & 63;
        if (wv < 4) {   // softmax per head
            float v0 = sc[wv * 128 + ln];
            float v1 = (ln < SEQ - 64) ? sc[wv * 128 + 64 + ln] : -1e30f;
            float m = fmaxf(v0, v1);
            #pragma unroll
            for (int off = 32; off; off >>= 1) m = fmaxf(m, __shfl_xor(m, off));
            float e0 = __expf(v0 - m);
            float e1 = (ln < SEQ - 64) ? __expf(v1 - m) : 0.f;
            float ss = e0 + e1;
            #pragma unroll
            for (int off = 32; off; off >>= 1) ss += __shfl_xor(ss, off);
            float inv = 1.f / ss;
            wsm[wv * 128 + ln] = e0 * inv;
            if (ln < SEQ - 64) wsm[wv * 128 + 64 + ln] = e1 * inv;
        }
        __syncthreads();
        {   // weighted sum: all 8 waves, s-range split in halves per head
            const int n = wv & 3, half = wv >> 2;
            float a0 = 0.f, a1 = 0.f, a2 = 0.f, a3 = 0.f;
            const int sBeg = half * 50, sEnd = sBeg + 50;
            #pragma unroll 5
            for (int s = sBeg; s < sEnd; ++s) {
                f16x4 e4 = *(const f16x4*)&encs[s * ENC + ln * 4];
                float w = wsm[n * 128 + s];
                a0 += w * (float)e4.x; a1 += w * (float)e4.y;
                a2 += w * (float)e4.z; a3 += w * (float)e4.w;
            }
            f32x4 pv; pv[0] = a0; pv[1] = a1; pv[2] = a2; pv[3] = a3;
            part[wv * 64 + ln] = pv;
        }
        __syncthreads();
        if (tid < 128) {   // repack: 8 consecutive e per thread -> one 16B store
            int n = tid >> 5, t8 = tid & 31;
            f32x4 a  = part[n * 64 + t8 * 2];
            f32x4 b2 = part[n * 64 + t8 * 2 + 1];
            f32x4 c  = part[(n + 4) * 64 + t8 * 2];
            f32x4 d  = part[(n + 4) * 64 + t8 * 2 + 1];
            f16x8 o;
            o[0] = (_Float16)(a[0] + c[0]); o[1] = (_Float16)(a[1] + c[1]);
            o[2] = (_Float16)(a[2] + c[2]); o[3] = (_Float16)(a[3] + c[3]);
            o[4] = (_Float16)(b2[0] + d[0]); o[5] = (_Float16)(b2[1] + d[1]);
            o[6] = (_Float16)(b2[2] + d[2]); o[7] = (_Float16)(b2[3] + d[3]);
            st_sc_b128(&eb[(size_t)b * 1088 + n * 256 + t8 * 8],
                       __builtin_bit_cast(u32x4, o));
        } else if (tid < 144) {
            int k = tid - 128;
            float4 zv = *(const float4*)&z[((size_t)b * TT + t) * 64 + k * 4];
            f16x4 zh;
            zh.x = (_Float16)zv.x; zh.y = (_Float16)zv.y;
            zh.z = (_Float16)zv.z; zh.w = (_Float16)zv.w;
            st_sc_b64(&eb[(size_t)b * 1088 + 1024 + k * 4],
                      __builtin_bit_cast(u32x2, zh));
        }
        __syncthreads();   // protect encs/part before next batch overwrites
    }
}

// ---------------------------------------------------------------- LSTM phase
// Gates GEMM (64x128 tile, BK=128, rows h*4+gate) + fused elementwise.
// c-state lives in cr[8] registers on threads <256 (thread -> (row, 8-h-chunk)
// mapping is static across all 30 steps). h written as packed 16B stores to hA
// only (disjoint from this phase's GEMM inputs -> race-free).
DEVI void lstm_phase(char* smem, const _Float16* __restrict__ X,
                     const _Float16* __restrict__ W, const float* __restrict__ bias,
                     float (&cr)[8], _Float16* __restrict__ hA, int ldA,
                     int bm0, int bn0) {
    f32x4 acc[4] = {};
    gemm_core_db<512, 64, 128, 128, 32, 32, true>(smem, X, 1024, W, 1024, 1024, bm0, bn0, acc);
    float* accs = (float*)smem;   // [64][132]
    const int tid = threadIdx.x, wave = tid >> 6, lane = tid & 63;
    const int wm = wave & 1, wn = wave >> 1, q = lane >> 4, m15 = lane & 15;
    #pragma unroll
    for (int i = 0; i < 2; ++i) {
        #pragma unroll
        for (int j = 0; j < 2; ++j) {
            int cl = wn * 32 + j * 16 + m15;
            float bv = bias[bn0 + cl];
            #pragma unroll
            for (int r = 0; r < 4; ++r) {
                int rl = wm * 32 + i * 16 + q * 4 + r;
                accs[rl * 132 + cl] = acc[i * 2 + j][r] + bv;
            }
        }
    }
    __syncthreads();
    if (tid < 256) {   // (row bl, 8-h chunk ch): 64 x 4 = 256 work items
        int bl = tid >> 2, ch = tid & 3;
        const float4* gp = (const float4*)&accs[bl * 132 + ch * 32];  // i,f,g,o x8
        f16x8 hv;
        #pragma unroll
        for (int j = 0; j < 8; ++j) {
            float4 g4 = gp[j];
            float cn = sigm(g4.y) * cr[j] + sigm(g4.x) * tanh_f(g4.z);
            cr[j] = cn;
            hv[j] = (_Float16)(sigm(g4.w) * tanh_f(cn));
        }
        int h0 = (bn0 >> 2) + ch * 8, gb = bm0 + bl;
        st_sc_b128(&hA[(size_t)gb * ldA + h0], __builtin_bit_cast(u32x4, hv));
    }
    __syncthreads();
}

// ---------------------------------------------------------------- fc2 chain (512 thr, 16 batches)
DEVI void fc2_512(char* smem, const _Float16* __restrict__ h2n,
                  const _Float16* __restrict__ Wa, const float* __restrict__ ab,
                  const _Float16* __restrict__ Wb, const float* __restrict__ bb,
                  const _Float16* __restrict__ Wc, const float* __restrict__ cb,
                  float* __restrict__ out, int b0, int t) {
    _Float16* h2s = (_Float16*)smem;       // [16][520]
    _Float16* y1s = h2s + 16 * 520;        // [16][264]
    _Float16* y2s = y1s + 16 * 264;        // [16][136]
    const int tid = threadIdx.x, wave = tid >> 6, lane = tid & 63;
    const int q = lane >> 4, m15 = lane & 15;
    u32x4 hv[2];
    #pragma unroll
    for (int c = 0; c < 2; ++c) {
        int cc = tid + c * 512, row = cc >> 6, col = (cc & 63) * 8;
        hv[c] = ld_sc_b128(&h2n[(size_t)(b0 + row) * 512 + col]);
    }
    wait_vm0();
    #pragma unroll
    for (int c = 0; c < 2; ++c) {
        int cc = tid + c * 512, row = cc >> 6, col = (cc & 63) * 8;
        *(u32x4*)&h2s[row * 520 + col] = hv[c];
    }
    __syncthreads();
    {   // y1[16,256] = lrelu(h2 @ Wa^T + ab); wave handles 32 cols
        f32x4 acc[2] = {};
        #pragma unroll 4
        for (int kk = 0; kk < 16; ++kk) {
            f16x8 af = *(const f16x8*)&h2s[m15 * 520 + kk * 32 + q * 8];
            #pragma unroll
            for (int j = 0; j < 2; ++j) {
                int n = wave * 32 + j * 16 + m15;
                f16x8 bf = *(const f16x8*)&Wa[(size_t)n * 512 + kk * 32 + q * 8];
                acc[j] = __builtin_amdgcn_mfma_f32_16x16x32_f16(af, bf, acc[j], 0, 0, 0);
            }
        }
        #pragma unroll
        for (int j = 0; j < 2; ++j) {
            int col = wave * 32 + j * 16 + m15;
            float bv = ab[col];
            #pragma unroll
            for (int r = 0; r < 4; ++r)
                y1s[(q * 4 + r) * 264 + col] = (_Float16)lrelu(acc[j][r] + bv);
        }
    }
    __syncthreads();
    {   // y2[16,128] = lrelu(y1 @ Wb^T + bb); wave handles 16 cols
        f32x4 acc[1] = {};
        #pragma unroll
        for (int kk = 0; kk < 8; ++kk) {
            f16x8 af = *(const f16x8*)&y1s[m15 * 264 + kk * 32 + q * 8];
            int n = wave * 16 + m15;
            f16x8 bf = *(const f16x8*)&Wb[(size_t)n * 256 + kk * 32 + q * 8];
            acc[0] = __builtin_amdgcn_mfma_f32_16x16x32_f16(af, bf, acc[0], 0, 0, 0);
        }
        int col = wave * 16 + m15;
        float bv = bb[col];
        #pragma unroll
        for (int r = 0; r < 4; ++r)
            y2s[(q * 4 + r) * 136 + col] = (_Float16)lrelu(acc[0][r] + bv);
    }
    __syncthreads();
    if (tid < 32) {   // y3: 16 batches x 2 outs, tanh; out is cached (host-read only)
        int r = tid >> 1, o = tid & 1;
        float acc = cb[o];
        #pragma unroll 8
        for (int k = 0; k < 128; ++k)
            acc += (float)Wc[o * 128 + k] * (float)y2s[r * 136 + k];
        out[((size_t)(b0 + r) * TT + t) * 2 + o] = tanhf(acc);
    }
}

// ---------------------------------------------------------------- persistent decoder
struct DecP {
    const _Float16* encH;
    const float* z;
    _Float16* eb;
    const _Float16* Wfc1;  const float* biasf;
    const _Float16* L1W;   const float* L1b;
    const _Float16* L2W;   const float* L2b;
    const _Float16* C_h;   const float* d_f;  const _Float16* d_h;
    const _Float16* fa;    const float* fab;
    const _Float16* fb;    const float* fbb;
    const _Float16* fcw;   const float* fcb;
    _Float16* xh1;  _Float16* xh2;  _Float16* h2n;  _Float16* G;
    float* out;
    unsigned* bars;
};

__global__ __launch_bounds__(512, 1) void decoder(DecP p) {
    __shared__ __align__(16) char smem[71680];
    const int blk = blockIdx.x, tid = threadIdx.x;
    const int grp = blk >> 4, sub = blk & 15;   // 16 groups x 16 blocks; group owns 64 batches
    const int b0a = blk * 4;                    // this block's 4 attn batches
    const int bm0 = grp * 64;                   // GEMM row tile
    float c1r[8] = {}, c2r[8] = {};
    unsigned want = 0;
    if (tid < 128) {   // G(0) = broadcast d (q-proj of h2=0); 16B bypass stores
        u32x4 v = *(const u32x4*)&p.d_h[tid * 8];
        #pragma unroll
        for (int i = 0; i < 4; ++i)
            st_sc_b128(&p.G[(size_t)(b0a + i) * 1024 + tid * 8], v);
    }
    wait_vm0();
    __syncthreads();
    for (int t = 0; t < TT; ++t) {
        // A: attention (4 batches, enc reg-prefetch double buffer)
        attn_phase(smem, p.G, p.encH, p.z, p.eb, b0a, t);
        gbar(p.bars, grp, ++want);
        // B: fc1 = lrelu(eb @ Wfc1^T + biasf) -> xh1[:, :512]
        {
            f32x4 acc[1] = {};
            gemm_core_db<512, 64, 32, 64, 16, 16, true>(smem, p.eb, 1088, p.Wfc1, 1088, 1088,
                                                        bm0, sub * 32, acc);
            epi_staged<512, 64, 32, 16, 16, 1>(smem, acc, p.biasf, p.xh1, 1024, bm0, sub * 32);
        }
        gbar(p.bars, grp, ++want);
        // C: LSTM1, X = [fc1out | h1(t-1)]; h1(t) -> xh2[:, :512] only (race-free)
        lstm_phase(smem, p.xh1, p.L1W, p.L1b, c1r, p.xh2, 1024, bm0, sub * 128);
        gbar(p.bars, grp, ++want);
        // D: LSTM2, X = [h1(t) | h2(t-1)]; h2(t) -> h2n only (race-free)
        lstm_phase(smem, p.xh2, p.L2W, p.L2b, c2r, p.h2n, 512, bm0, sub * 128);
        gbar(p.bars, grp, ++want);
        // E: h-state copies + q-projection for next step (skip on last), fc2 output
        if (t < TT - 1) {
            {   // copies: tid<256 h1 -> lstm1 input, tid>=256 h2 -> lstm2 input
                int idx = tid & 255, row = idx >> 2, ch = idx & 3;
                size_t ro = (size_t)(bm0 + row);
                const void* src; void* dst;
                if (tid < 256) {
                    src = &p.xh2[ro * 1024 + sub * 32 + ch * 8];
                    dst = &p.xh1[ro * 1024 + 512 + sub * 32 + ch * 8];
                } else {
                    src = &p.h2n[ro * 512 + sub * 32 + ch * 8];
                    dst = &p.xh2[ro * 1024 + 512 + sub * 32 + ch * 8];
                }
                u32x4 v = ld_sc_b128(src);
                wait_vm0();
                st_sc_b128(dst, v);
            }
            f32x4 acc[2] = {};
            gemm_core_db<512, 64, 64, 128, 16, 32, true>(smem, p.h2n, 512, p.C_h, 512, 512,
                                                         bm0, sub * 64, acc);
            epi_staged<512, 64, 64, 16, 32, 0>(smem, acc, p.d_f, p.G, 1024, bm0, sub * 64);
        }
        if (sub < 4)
            fc2_512(smem, p.h2n, p.fa, p.fab, p.fb, p.fbb, p.fcw, p.fcb,
                    p.out, bm0 + sub * 16, t);
        if (t < TT - 1) gbar(p.bars, grp, ++want);
    }
}

// ---------------------------------------------------------------- launch
extern "C" void kernel_launch(void* const* d_in, const int* in_sizes, int n_in,
                              void* d_out, int out_size, void* d_ws, size_t ws_size,
                              hipStream_t stream) {
    const float* encoded = (const float*)d_in[0];
    const float* z       = (const float*)d_in[1];
    const float* q_w     = (const float*)d_in[2];
    const float* k_w     = (const float*)d_in[3];
    const float* v_w     = (const float*)d_in[4];
    const float* q_b     = (const float*)d_in[5];
    // d_in[6] (k_b): softmax-invariant — dropped exactly.
    const float* v_b     = (const float*)d_in[7];
    const float* out_w   = (const float*)d_in[8];
    const float* out_b   = (const float*)d_in[9];
    const float* fc1_w   = (const float*)d_in[10];
    const float* fc1_b   = (const float*)d_in[11];
    const float* l1_wih  = (const float*)d_in[12];
    const float* l1_whh  = (const float*)d_in[13];
    const float* l1_bih  = (const float*)d_in[14];
    const float* l1_bhh  = (const float*)d_in[15];
    const float* l2_wih  = (const float*)d_in[16];
    const float* l2_whh  = (const float*)d_in[17];
    const float* l2_bih  = (const float*)d_in[18];
    const float* l2_bhh  = (const float*)d_in[19];
    const float* fc2a_w  = (const float*)d_in[20];
    const float* fc2a_b  = (const float*)d_in[21];
    const float* fc2b_w  = (const float*)d_in[22];
    const float* fc2b_b  = (const float*)d_in[23];
    const float* fc2c_w  = (const float*)d_in[24];
    const float* fc2c_b  = (const float*)d_in[25];
    float* out = (float*)d_out;

    char* p = (char*)d_ws;
    auto take = [&](size_t bytes) { char* r = p; p += (bytes + 255) & ~(size_t)255; return r; };
    _Float16* encH  = (_Float16*)take(52428800);   // [1024,100,256] fp16
    _Float16* C_h   = (_Float16*)take(1048576);    // [1024,512]
    _Float16* Wfc1  = (_Float16*)take(1114112);    // [512,1088]
    _Float16* L1W   = (_Float16*)take(4194304);    // [2048,1024] rows h*4+g
    _Float16* L2W   = (_Float16*)take(4194304);
    _Float16* fc2a16= (_Float16*)take(262144);     // [256,512]
    _Float16* fc2b16= (_Float16*)take(65536);      // [128,256]
    _Float16* fc2c16= (_Float16*)take(512);        // [2,128]
    _Float16* eb    = (_Float16*)take(2228224);    // [1024,1088]
    _Float16* h2n   = (_Float16*)take(1048576);    // [1024,512]  h2(t)
    char* zreg = p;                                // ---- zero region (4 MB + 4 KB) ----
    _Float16* xh1 = (_Float16*)take(2097152);      // [1024,1024] = [fc1out | h1]
    _Float16* xh2 = (_Float16*)take(2097152);      // [1024,1024] = [h1 | h2]
    unsigned* bars = (unsigned*)take(4096);        // per-group barrier counters/flags
    // ---- end zero region ----
    _Float16* G   = (_Float16*)take(2097152);      // [1024,1024] (init in-kernel)
    float* A      = (float*)take(1048576);
    float* d_f    = (float*)take(4096);
    _Float16* d_h = (_Float16*)take(2048);
    float* biasf  = (float*)take(2048);
    float* L1b    = (float*)take(8192);
    float* L2b    = (float*)take(8192);
    (void)in_sizes; (void)n_in; (void)out_size; (void)ws_size;

    zero_ws<<<1025, 256, 0, stream>>>((uint4*)zreg);   // xh1+xh2+bars = 1025*4096 B
    conv_enc<<<25600, 256, 0, stream>>>((const float4*)encoded, (f16x4*)encH);
    prep_qk<<<1024, 256, 0, stream>>>(k_w, q_w, q_b, C_h, d_f, d_h);
    prep_A<<<512, 256, 0, stream>>>(fc1_w, out_w, A);
    prep_wfc1<<<512, 256, 0, stream>>>(A, v_w, v_b, fc1_w, out_b, fc1_b, Wfc1, biasf);
    prep_lstm<<<8192, 256, 0, stream>>>(l1_wih, l1_whh, l1_bih, l1_bhh, L1W, L1b);
    prep_lstm<<<8192, 256, 0, stream>>>(l2_wih, l2_whh, l2_bih, l2_bhh, L2W, L2b);
    prep_fc2c<<<641, 256, 0, stream>>>(fc2a_w, fc2b_w, fc2c_w, fc2a16, fc2b16, fc2c16);

    DecP dp;
    dp.encH = encH; dp.z = z; dp.eb = eb;
    dp.Wfc1 = Wfc1; dp.biasf = biasf;
    dp.L1W = L1W; dp.L1b = L1b; dp.L2W = L2W; dp.L2b = L2b;
    dp.C_h = C_h; dp.d_f = d_f; dp.d_h = d_h;
    dp.fa = fc2a16; dp.fab = fc2a_b; dp.fb = fc2b16; dp.fbb = fc2b_b;
    dp.fcw = fc2c16; dp.fcb = fc2c_b;
    dp.xh1 = xh1; dp.xh2 = xh2; dp.h2n = h2n; dp.G = G;
    dp.out = out; dp.bars = bars;
    void* params[] = { &dp };
    // Cooperative launch guarantees co-residency for the in-kernel barrier.
    // 256 blocks x 512 thr, 71680 B LDS -> 1 block/CU, always satisfiable.
    if (hipLaunchCooperativeKernel((const void*)decoder, dim3(256), dim3(512),
                                   params, 0, stream) != hipSuccess) {
        // Fallback: plain launch. grid(256) <= #CUs => all workgroups resident
        // at dispatch; per-group barrier remains safe.
        decoder<<<256, 512, 0, stream>>>(dp);
    }
}

// Round 5
// 3131.929 us; speedup vs baseline: 2.1455x; 1.0565x over previous
//
#include <hip/hip_runtime.h>

// Generator_78683800862785: attention+LSTM decoder, BS=1024, T=30.
// R5: kill the 62 MB/step post-L2 fetch (R4: FETCH 1.92 GB/dispatch = encH
// 50MB re-read every step + weights evicted by the enc stream).
//  - enc resident: per block, batch0 enc in persistent LDS (51200B), batches
//    1..3 in 84 persistent VGPRs (er[3][7], statically indexed), staged to the
//    LDS scratch per step. encH is read ONCE per kernel. Weight working set
//    per XCD (~1.3MB: subs {x, x+8}) now stays L2-resident across steps.
//  - h-state double-buffered (xh1[2]/xh2[2]): LSTM writes h(t) to next step's
//    input buffer directly (2nd packed store); phase-E copy deleted.
//  - barrier: per-block slot stores (monotonic, one line/group) + 4xb128
//    bypass poll; replaces the 16-deep cross-XCD atomic RMW chain.
//  - __launch_bounds__(512,2) caps VGPR at 256 (demand ~214).
// Coherence model from R2/R4 (verified passing): sc0sc1 bypass for cross-block
// activations, cached path for weights, vmcnt(0) drain before arrival.

#define DEVI __device__ __forceinline__

typedef _Float16 f16x8 __attribute__((ext_vector_type(8)));
typedef _Float16 f16x4 __attribute__((ext_vector_type(4)));
typedef float    f32x4 __attribute__((ext_vector_type(4)));
typedef unsigned u32x4 __attribute__((ext_vector_type(4)));
typedef unsigned u32x2 __attribute__((ext_vector_type(2)));

#define BSZ 1024
#define SEQ 100
#define ENC 256
#define HID 512
#define LAT 64
#define TT  30

// ---------------------------------------------------------------- utilities
DEVI float lrelu(float v) { return v >= 0.f ? v : 0.2f * v; }
DEVI float sigm(float x)  { return 1.f / (1.f + __expf(-x)); }
DEVI float tanh_f(float x){ return 1.f - 2.f / (1.f + __expf(2.f * x)); }
DEVI unsigned umin2(unsigned a, unsigned b) { return a < b ? a : b; }

// ---- system-coherent (cache-bypass) access helpers. Loads are issued async;
// caller MUST call wait_vm0() before consuming results. Stores fire-and-forget;
// drained by wait_vm0() in gbar before arrival. Value-typed so asm operands
// are always registers.
DEVI void wait_vm0() { asm volatile("s_waitcnt vmcnt(0)" ::: "memory"); }
DEVI u32x4 ld_sc_b128(const void* p) {
    u32x4 d;
    asm volatile("global_load_dwordx4 %0, %1, off sc0 sc1" : "=v"(d) : "v"(p) : "memory");
    return d;
}
DEVI void st_sc_b128(void* p, u32x4 v) {
    asm volatile("global_store_dwordx4 %0, %1, off sc0 sc1" :: "v"(p), "v"(v) : "memory");
}
DEVI void st_sc_b64(void* p, u32x2 v) {
    asm volatile("global_store_dwordx2 %0, %1, off sc0 sc1" :: "v"(p), "v"(v) : "memory");
}
DEVI void st_sc_b32(void* p, unsigned v) {
    asm volatile("global_store_dword %0, %1, off sc0 sc1" :: "v"(p), "v"(v) : "memory");
}

// ---------------------------------------------------------------- setup kernels
__global__ __launch_bounds__(256) void zero_ws(uint4* __restrict__ p) {
    uint4 z; z.x = z.y = z.z = z.w = 0u;
    p[(size_t)blockIdx.x * 256 + threadIdx.x] = z;
}

__global__ __launch_bounds__(256) void conv_enc(const float4* __restrict__ src,
                                                f16x4* __restrict__ dst) {
    size_t i = (size_t)blockIdx.x * 256 + threadIdx.x;
    float4 v = src[i];
    f16x4 h;
    h.x = (_Float16)v.x; h.y = (_Float16)v.y; h.z = (_Float16)v.z; h.w = (_Float16)v.w;
    dst[i] = h;
}

// C[ne,h] = scale * sum_d k_w[n*128+d, e] * q_w[n*128+d, h]   (fp16 out)
// d[ne]   = scale * sum_d k_w[n*128+d, e] * q_b[n*128+d]
__global__ __launch_bounds__(256) void prep_qk(const float* __restrict__ k_w,
                                               const float* __restrict__ q_w,
                                               const float* __restrict__ q_b,
                                               _Float16* __restrict__ C_h,
                                               float* __restrict__ d_f,
                                               _Float16* __restrict__ d_h) {
    const int ne = blockIdx.x, n = ne >> 8, e = ne & 255, tid = threadIdx.x;
    const float scale = 0.08838834764831845f;  // 1/sqrt(128)
    float a0 = 0.f, a1 = 0.f;
    for (int dd = 0; dd < 128; ++dd) {
        float kv = k_w[(n * 128 + dd) * 256 + e];
        a0 += kv * q_w[(n * 128 + dd) * 512 + tid];
        a1 += kv * q_w[(n * 128 + dd) * 512 + 256 + tid];
    }
    C_h[(size_t)ne * 512 + tid]       = (_Float16)(scale * a0);
    C_h[(size_t)ne * 512 + 256 + tid] = (_Float16)(scale * a1);
    float pq = (tid < 128) ? k_w[(n * 128 + tid) * 256 + e] * q_b[n * 128 + tid] : 0.f;
    #pragma unroll
    for (int off = 32; off; off >>= 1) pq += __shfl_down(pq, off);
    __shared__ float red[4];
    if ((tid & 63) == 0) red[tid >> 6] = pq;
    __syncthreads();
    if (tid == 0) {
        float s = scale * (red[0] + red[1] + red[2] + red[3]);
        d_f[ne] = s; d_h[ne] = (_Float16)s;
    }
}

// A[h,k] = sum_m fc1_w[h, m] * out_w[m, k]
__global__ __launch_bounds__(256) void prep_A(const float* __restrict__ fc1_w,
                                              const float* __restrict__ out_w,
                                              float* __restrict__ A) {
    const int h = blockIdx.x, tid = threadIdx.x;
    float a0 = 0.f, a1 = 0.f;
    for (int m = 0; m < 512; ++m) {
        float fv = fc1_w[h * 576 + m];
        a0 += fv * out_w[m * 512 + tid];
        a1 += fv * out_w[m * 512 + 256 + tid];
    }
    A[(size_t)h * 512 + tid]       = a0;
    A[(size_t)h * 512 + 256 + tid] = a1;
}

// Wfc1[h, n*256+e] = sum_d A[h, n*128+d]*v_w[n*128+d, e]; cols 1024..1087 = fc1_w[h,512+l]
__global__ __launch_bounds__(256) void prep_wfc1(const float* __restrict__ A,
                                                 const float* __restrict__ v_w,
                                                 const float* __restrict__ v_b,
                                                 const float* __restrict__ fc1_w,
                                                 const float* __restrict__ out_b,
                                                 const float* __restrict__ fc1_b,
                                                 _Float16* __restrict__ Wfc1,
                                                 float* __restrict__ biasf) {
    const int h = blockIdx.x, tid = threadIdx.x;
    #pragma unroll
    for (int g = 0; g < 4; ++g) {
        float acc = 0.f;
        for (int dd = 0; dd < 128; ++dd)
            acc += A[h * 512 + g * 128 + dd] * v_w[(g * 128 + dd) * 256 + tid];
        Wfc1[(size_t)h * 1088 + g * 256 + tid] = (_Float16)acc;
    }
    if (tid < 64)
        Wfc1[(size_t)h * 1088 + 1024 + tid] = (_Float16)fc1_w[h * 576 + 512 + tid];
    float ps = A[h * 512 + tid] * v_b[tid] + A[h * 512 + 256 + tid] * v_b[256 + tid]
             + fc1_w[h * 576 + tid] * out_b[tid] + fc1_w[h * 576 + 256 + tid] * out_b[256 + tid];
    #pragma unroll
    for (int off = 32; off; off >>= 1) ps += __shfl_down(ps, off);
    __shared__ float red[4];
    if ((tid & 63) == 0) red[tid >> 6] = ps;
    __syncthreads();
    if (tid == 0) biasf[h] = red[0] + red[1] + red[2] + red[3] + fc1_b[h];
}

// LSTM weights: concat [wih|whh] -> fp16 [2048 x 1024], rows reordered to h*4+gate.
__global__ __launch_bounds__(256) void prep_lstm(const float* __restrict__ wih,
                                                 const float* __restrict__ whh,
                                                 const float* __restrict__ bih,
                                                 const float* __restrict__ bhh,
                                                 _Float16* __restrict__ Wc,
                                                 float* __restrict__ bc) {
    int idx = blockIdx.x * 256 + threadIdx.x;  // 2,097,152
    int rp = idx >> 10, cc = idx & 1023;
    int h = rp >> 2, g = rp & 3;
    int rsrc = g * 512 + h;
    float v = (cc < 512) ? wih[(size_t)rsrc * 512 + cc] : whh[(size_t)rsrc * 512 + cc - 512];
    Wc[idx] = (_Float16)v;
    if (idx < 2048) {
        int h2 = idx >> 2, g2 = idx & 3;
        bc[idx] = bih[g2 * 512 + h2] + bhh[g2 * 512 + h2];
    }
}

// fc2 weights -> straight fp16 casts (no transpose; GEMMs run X @ W^T).
__global__ __launch_bounds__(256) void prep_fc2c(const float* __restrict__ aw,
                                                 const float* __restrict__ bw,
                                                 const float* __restrict__ cw,
                                                 _Float16* __restrict__ a16,
                                                 _Float16* __restrict__ b16,
                                                 _Float16* __restrict__ c16) {
    int i = blockIdx.x * 256 + threadIdx.x;
    if (i < 131072) a16[i] = (_Float16)aw[i];
    else if (i < 163840) b16[i - 131072] = (_Float16)bw[i - 131072];
    else if (i < 164096) c16[i - 163840] = (_Float16)cw[i - 163840];
}

// ---------------------------------------------------------------- GEMM core (reg double-buffered)
// Computes out = X @ W^T on a BMxBN tile. W row-major [N,K].
// BYPX: X loads are system-coherent bypass (activation tensors); W stays cached.
// acc layout per 16x16 tile: row=(lane>>4)*4+r, col=lane&15.
template <int NTHR, int BM, int BN, int BK, int WM, int WN, bool BYPX>
DEVI void gemm_core_db(char* smem_raw, const _Float16* __restrict__ X, int ldx,
                       const _Float16* __restrict__ W, int ldw, int K,
                       int bm0, int bn0, f32x4* acc) {
    constexpr int LDT = BK + 8;
    _Float16* Xs = (_Float16*)smem_raw;
    _Float16* Ws = Xs + BM * LDT;
    const int tid = threadIdx.x, wave = tid >> 6, lane = tid & 63;
    constexpr int WROWS = BM / WM;
    static_assert(WROWS * (BN / WN) == NTHR / 64, "wave grid mismatch");
    const int wm = wave % WROWS, wn = wave / WROWS;
    constexpr int MT = WM / 16, NT = WN / 16;
    const int q = lane >> 4, m15 = lane & 15;
    constexpr int CPR = BK / 8;
    constexpr int XCH = BM * CPR, WCH = BN * CPR;
    constexpr int XPT = (XCH + NTHR - 1) / NTHR;
    constexpr int WPT = (WCH + NTHR - 1) / NTHR;
    u32x4 xr[XPT], wr[WPT];
    auto ldregs = [&](int k0) {
        #pragma unroll
        for (int c = 0; c < XPT; ++c) {
            int cc = tid + c * NTHR;
            if ((XCH % NTHR) == 0 || cc < XCH) {
                int row = cc / CPR, col = (cc % CPR) * 8;
                const void* px = &X[(size_t)(bm0 + row) * ldx + k0 + col];
                if (BYPX) xr[c] = ld_sc_b128(px);
                else      xr[c] = *(const u32x4*)px;
            }
        }
        #pragma unroll
        for (int c = 0; c < WPT; ++c) {
            int cc = tid + c * NTHR;
            if ((WCH % NTHR) == 0 || cc < WCH) {
                int row = cc / CPR, col = (cc % CPR) * 8;
                wr[c] = *(const u32x4*)&W[(size_t)(bn0 + row) * ldw + k0 + col];
            }
        }
    };
    ldregs(0);
    for (int k0 = 0; k0 < K; k0 += BK) {
        if (BYPX) wait_vm0();   // asm loads of this tile are now complete
        #pragma unroll
        for (int c = 0; c < XPT; ++c) {
            int cc = tid + c * NTHR;
            if ((XCH % NTHR) == 0 || cc < XCH) {
                int row = cc / CPR, col = (cc % CPR) * 8;
                *(u32x4*)&Xs[row * LDT + col] = xr[c];
            }
        }
        #pragma unroll
        for (int c = 0; c < WPT; ++c) {
            int cc = tid + c * NTHR;
            if ((WCH % NTHR) == 0 || cc < WCH) {
                int row = cc / CPR, col = (cc % CPR) * 8;
                *(u32x4*)&Ws[row * LDT + col] = wr[c];
            }
        }
        __syncthreads();
        if (k0 + BK < K) ldregs(k0 + BK);   // overlap next-tile loads with MFMA phase
        #pragma unroll
        for (int kk = 0; kk < BK / 32; ++kk) {
            f16x8 af[MT], bf[NT];
            #pragma unroll
            for (int i = 0; i < MT; ++i)
                af[i] = *(const f16x8*)&Xs[(wm * WM + i * 16 + m15) * LDT + kk * 32 + q * 8];
            #pragma unroll
            for (int j = 0; j < NT; ++j)
                bf[j] = *(const f16x8*)&Ws[(wn * WN + j * 16 + m15) * LDT + kk * 32 + q * 8];
            #pragma unroll
            for (int i = 0; i < MT; ++i)
                #pragma unroll
                for (int j = 0; j < NT; ++j)
                    acc[i * NT + j] = __builtin_amdgcn_mfma_f32_16x16x32_f16(af[i], bf[j], acc[i * NT + j], 0, 0, 0);
        }
        __syncthreads();
    }
}

// Epilogue: stage tile (bias+act applied) in LDS, then packed 16B bypass stores.
template <int NTHR, int BM, int BN, int WM, int WN, int ACT>
DEVI void epi_staged(char* smem_raw, const f32x4* acc, const float* __restrict__ bias,
                     _Float16* __restrict__ out, int ldo, int bm0, int bn0) {
    constexpr int LDS_ = BN + 4;
    float* accs = (float*)smem_raw;
    const int tid = threadIdx.x, wave = tid >> 6, lane = tid & 63;
    constexpr int WROWS = BM / WM;
    const int wm = wave % WROWS, wn = wave / WROWS;
    constexpr int MT = WM / 16, NT = WN / 16;
    const int q = lane >> 4, m15 = lane & 15;
    #pragma unroll
    for (int i = 0; i < MT; ++i) {
        #pragma unroll
        for (int j = 0; j < NT; ++j) {
            int cl = wn * WN + j * 16 + m15;
            float bv = bias[bn0 + cl];
            #pragma unroll
            for (int r = 0; r < 4; ++r) {
                int rl = wm * WM + i * 16 + q * 4 + r;
                float v = acc[i * NT + j][r] + bv;
                if (ACT == 1) v = lrelu(v);
                accs[rl * LDS_ + cl] = v;
            }
        }
    }
    __syncthreads();
    constexpr int CH = BN / 8, ITEMS = BM * CH;
    #pragma unroll
    for (int base = 0; base < ITEMS; base += NTHR) {
        int idx = base + tid;
        if ((ITEMS % NTHR) == 0 || idx < ITEMS) {
            int row = idx / CH, ch = idx % CH;
            const float* src = &accs[row * LDS_ + ch * 8];
            f16x8 o;
            #pragma unroll
            for (int k = 0; k < 8; ++k) o[k] = (_Float16)src[k];
            st_sc_b128(&out[(size_t)(bm0 + row) * ldo + bn0 + ch * 8],
                       __builtin_bit_cast(u32x4, o));
        }
    }
    __syncthreads();
}

// ---------------------------------------------------------------- group barrier
// Per-block monotonic slot stores on one 64B line per group; one thread polls
// all 16 slots with 4 b128 bypass loads. No RMW chain, no resets, no cache
// maintenance (activations travel via sc0/sc1 bypass; vmcnt(0) drain precedes
// the slot store so data is visible before the arrival is).
DEVI void gbar(unsigned* bars, int grp, int sub, unsigned want) {
    wait_vm0();                     // drain this block's bypass stores
    __syncthreads();
    if (threadIdx.x == 0) {
        st_sc_b32(&bars[grp * 16 + sub], want);
        unsigned spins = 0;
        for (;;) {
            u32x4 a = ld_sc_b128(&bars[grp * 16 + 0]);
            u32x4 b = ld_sc_b128(&bars[grp * 16 + 4]);
            u32x4 c = ld_sc_b128(&bars[grp * 16 + 8]);
            u32x4 d = ld_sc_b128(&bars[grp * 16 + 12]);
            wait_vm0();
            unsigned mn = umin2(umin2(umin2(a[0], a[1]), umin2(a[2], a[3])),
                          umin2(umin2(umin2(b[0], b[1]), umin2(b[2], b[3])),
                          umin2(umin2(umin2(c[0], c[1]), umin2(c[2], c[3])),
                                umin2(umin2(d[0], d[1]), umin2(d[2], d[3])))));
            if (mn >= want) break;
            __builtin_amdgcn_s_sleep(1);
            if (++spins > (1u << 17)) break;   // safety valve
        }
        asm volatile("" ::: "memory");
    }
    __syncthreads();
}

// ---------------------------------------------------------------- attention
// Per block: 4 batches. Batch 0's enc lives in persistent LDS (loaded once at
// kernel start); batches 1..3 live in persistent VGPRs (er[3][7]) and are
// staged into the LDS scratch per step. No global enc traffic inside the t-loop.
DEVI void attn_one(const _Float16* encs, const _Float16* gs, float* sc, float* wsm,
                   f32x4* part, const float* __restrict__ z,
                   _Float16* __restrict__ eb, int gi, int b, int t) {
    const int tid = threadIdx.x;
    {   // scores: 32 groups of 16 lanes; group = (head n, s-offset)
        const int grpq = tid >> 4, l16 = tid & 15, n = grpq & 3, soff = grpq >> 2;
        const f16x8 g0 = *(const f16x8*)&gs[gi * 1024 + n * 256 + l16 * 8];
        const f16x8 g1 = *(const f16x8*)&gs[gi * 1024 + n * 256 + 128 + l16 * 8];
        for (int it = 0; it < 13; ++it) {
            int s = it * 8 + soff;
            if (s < SEQ) {
                const f16x8 e0 = *(const f16x8*)&encs[s * ENC + l16 * 8];
                const f16x8 e1 = *(const f16x8*)&encs[s * ENC + 128 + l16 * 8];
                float p = 0.f;
                #pragma unroll
                for (int j = 0; j < 8; ++j)
                    p += (float)e0[j] * (float)g0[j] + (float)e1[j] * (float)g1[j];
                p += __shfl_xor(p, 1); p += __shfl_xor(p, 2);
                p += __shfl_xor(p, 4); p += __shfl_xor(p, 8);
                if (l16 == 0) sc[n * 128 + s] = p;
            }
        }
    }
    __syncthreads();
    const int wv = tid >> 6, ln = tid & 63;
    if (wv < 4) {   // softmax per head
        float v0 = sc[wv * 128 + ln];
        float v1 = (ln < SEQ - 64) ? sc[wv * 128 + 64 + ln] : -1e30f;
        float m = fmaxf(v0, v1);
        #pragma unroll
        for (int off = 32; off; off >>= 1) m = fmaxf(m, __shfl_xor(m, off));
        float e0 = __expf(v0 - m);
        float e1 = (ln < SEQ - 64) ? __expf(v1 - m) : 0.f;
        float ss = e0 + e1;
        #pragma unroll
        for (int off = 32; off; off >>= 1) ss += __shfl_xor(ss, off);
        float inv = 1.f / ss;
        wsm[wv * 128 + ln] = e0 * inv;
        if (ln < SEQ - 64) wsm[wv * 128 + 64 + ln] = e1 * inv;
    }
    __syncthreads();
    {   // weighted sum: all 8 waves, s-range split in halves per head
        const int n = wv & 3, half = wv >> 2;
        float a0 = 0.f, a1 = 0.f, a2 = 0.f, a3 = 0.f;
        const int sBeg = half * 50, sEnd = sBeg + 50;
        #pragma unroll 5
        for (int s = sBeg; s < sEnd; ++s) {
            f16x4 e4 = *(const f16x4*)&encs[s * ENC + ln * 4];
            float w = wsm[n * 128 + s];
            a0 += w * (float)e4.x; a1 += w * (float)e4.y;
            a2 += w * (float)e4.z; a3 += w * (float)e4.w;
        }
        f32x4 pv; pv[0] = a0; pv[1] = a1; pv[2] = a2; pv[3] = a3;
        part[wv * 64 + ln] = pv;
    }
    __syncthreads();
    if (tid < 128) {   // repack: 8 consecutive e per thread -> one 16B store
        int n = tid >> 5, t8 = tid & 31;
        f32x4 a  = part[n * 64 + t8 * 2];
        f32x4 b2 = part[n * 64 + t8 * 2 + 1];
        f32x4 c  = part[(n + 4) * 64 + t8 * 2];
        f32x4 d  = part[(n + 4) * 64 + t8 * 2 + 1];
        f16x8 o;
        o[0] = (_Float16)(a[0] + c[0]); o[1] = (_Float16)(a[1] + c[1]);
        o[2] = (_Float16)(a[2] + c[2]); o[3] = (_Float16)(a[3] + c[3]);
        o[4] = (_Float16)(b2[0] + d[0]); o[5] = (_Float16)(b2[1] + d[1]);
        o[6] = (_Float16)(b2[2] + d[2]); o[7] = (_Float16)(b2[3] + d[3]);
        st_sc_b128(&eb[(size_t)b * 1088 + n * 256 + t8 * 8],
                   __builtin_bit_cast(u32x4, o));
    } else if (tid < 144) {
        int k = tid - 128;
        float4 zv = *(const float4*)&z[((size_t)b * TT + t) * 64 + k * 4];
        f16x4 zh;
        zh.x = (_Float16)zv.x; zh.y = (_Float16)zv.y;
        zh.z = (_Float16)zv.z; zh.w = (_Float16)zv.w;
        st_sc_b64(&eb[(size_t)b * 1088 + 1024 + k * 4],
                  __builtin_bit_cast(u32x2, zh));
    }
    __syncthreads();   // protect encs/sc/wsm/part before next batch reuses them
}

// LDS map: [encP 51200][scratch 71680]; scratch = [stage 51200][gs 8192]
// [sc 2048][wsm 2048][part 8192]. GEMM/epi/fc2 use scratch only.
DEVI void attn_phase(char* smem_all, u32x4 (&er)[3][7],
                     const _Float16* __restrict__ G, const float* __restrict__ z,
                     _Float16* __restrict__ eb, int b0, int t) {
    _Float16* encP  = (_Float16*)smem_all;
    char* scratch   = smem_all + 51200;
    _Float16* stage = (_Float16*)scratch;
    _Float16* gs    = (_Float16*)(scratch + 51200);
    float* sc       = (float*)(scratch + 59392);
    float* wsm      = (float*)(scratch + 61440);
    f32x4* part     = (f32x4*)(scratch + 63488);
    const int tid = threadIdx.x;
    {   // all 4 G rows (bypass: produced by other blocks last phase)
        int row = tid >> 7, idx = tid & 127;
        u32x4 gv = ld_sc_b128(&G[(size_t)(b0 + row) * 1024 + idx * 8]);
        wait_vm0();
        *(u32x4*)&gs[row * 1024 + idx * 8] = gv;
    }
    __syncthreads();
    attn_one(encP, gs, sc, wsm, part, z, eb, 0, b0, t);
    #pragma unroll
    for (int i = 0; i < 3; ++i) {
        {   // persistent regs -> LDS stage
            u32x4* dst = (u32x4*)stage;
            #pragma unroll
            for (int k = 0; k < 6; ++k) dst[tid + k * 512] = er[i][k];
            if (tid < 128) dst[tid + 3072] = er[i][6];
        }
        __syncthreads();
        attn_one(stage, gs, sc, wsm, part, z, eb, i + 1, b0 + 1 + i, t);
    }
}

// ---------------------------------------------------------------- LSTM phase
// Gates GEMM (64x128 tile, BK=128, rows h*4+gate) + fused elementwise.
// c-state in cr[8] registers on threads <256. h(t) written to BOTH this step's
// consumer buffer (hA) and next step's input buffer (hB) as packed 16B stores.
DEVI void lstm_phase(char* smem, const _Float16* __restrict__ X,
                     const _Float16* __restrict__ W, const float* __restrict__ bias,
                     float (&cr)[8], _Float16* __restrict__ hA, int ldA,
                     _Float16* __restrict__ hB, int ldB, int bm0, int bn0) {
    f32x4 acc[4] = {};
    gemm_core_db<512, 64, 128, 128, 32, 32, true>(smem, X, 1024, W, 1024, 1024, bm0, bn0, acc);
    float* accs = (float*)smem;   // [64][132]
    const int tid = threadIdx.x, wave = tid >> 6, lane = tid & 63;
    const int wm = wave & 1, wn = wave >> 1, q = lane >> 4, m15 = lane & 15;
    #pragma unroll
    for (int i = 0; i < 2; ++i) {
        #pragma unroll
        for (int j = 0; j < 2; ++j) {
            int cl = wn * 32 + j * 16 + m15;
            float bv = bias[bn0 + cl];
            #pragma unroll
            for (int r = 0; r < 4; ++r) {
                int rl = wm * 32 + i * 16 + q * 4 + r;
                accs[rl * 132 + cl] = acc[i * 2 + j][r] + bv;
            }
        }
    }
    __syncthreads();
    if (tid < 256) {   // (row bl, 8-h chunk ch): 64 x 4 = 256 work items
        int bl = tid >> 2, ch = tid & 3;
        const float4* gp = (const float4*)&accs[bl * 132 + ch * 32];  // i,f,g,o x8
        f16x8 hv;
        #pragma unroll
        for (int j = 0; j < 8; ++j) {
            float4 g4 = gp[j];
            float cn = sigm(g4.y) * cr[j] + sigm(g4.x) * tanh_f(g4.z);
            cr[j] = cn;
            hv[j] = (_Float16)(sigm(g4.w) * tanh_f(cn));
        }
        int h0 = (bn0 >> 2) + ch * 8, gb = bm0 + bl;
        u32x4 hb = __builtin_bit_cast(u32x4, hv);
        st_sc_b128(&hA[(size_t)gb * ldA + h0], hb);
        st_sc_b128(&hB[(size_t)gb * ldB + h0], hb);
    }
    __syncthreads();
}

// ---------------------------------------------------------------- fc2 chain (512 thr, 16 batches)
DEVI void fc2_512(char* smem, const _Float16* __restrict__ h2n,
                  const _Float16* __restrict__ Wa, const float* __restrict__ ab,
                  const _Float16* __restrict__ Wb, const float* __restrict__ bb,
                  const _Float16* __restrict__ Wc, const float* __restrict__ cb,
                  float* __restrict__ out, int b0, int t) {
    _Float16* h2s = (_Float16*)smem;       // [16][520]
    _Float16* y1s = h2s + 16 * 520;        // [16][264]
    _Float16* y2s = y1s + 16 * 264;        // [16][136]
    const int tid = threadIdx.x, wave = tid >> 6, lane = tid & 63;
    const int q = lane >> 4, m15 = lane & 15;
    u32x4 hv[2];
    #pragma unroll
    for (int c = 0; c < 2; ++c) {
        int cc = tid + c * 512, row = cc >> 6, col = (cc & 63) * 8;
        hv[c] = ld_sc_b128(&h2n[(size_t)(b0 + row) * 512 + col]);
    }
    wait_vm0();
    #pragma unroll
    for (int c = 0; c < 2; ++c) {
        int cc = tid + c * 512, row = cc >> 6, col = (cc & 63) * 8;
        *(u32x4*)&h2s[row * 520 + col] = hv[c];
    }
    __syncthreads();
    {   // y1[16,256] = lrelu(h2 @ Wa^T + ab); wave handles 32 cols
        f32x4 acc[2] = {};
        #pragma unroll 4
        for (int kk = 0; kk < 16; ++kk) {
            f16x8 af = *(const f16x8*)&h2s[m15 * 520 + kk * 32 + q * 8];
            #pragma unroll
            for (int j = 0; j < 2; ++j) {
                int n = wave * 32 + j * 16 + m15;
                f16x8 bf = *(const f16x8*)&Wa[(size_t)n * 512 + kk * 32 + q * 8];
                acc[j] = __builtin_amdgcn_mfma_f32_16x16x32_f16(af, bf, acc[j], 0, 0, 0);
            }
        }
        #pragma unroll
        for (int j = 0; j < 2; ++j) {
            int col = wave * 32 + j * 16 + m15;
            float bv = ab[col];
            #pragma unroll
            for (int r = 0; r < 4; ++r)
                y1s[(q * 4 + r) * 264 + col] = (_Float16)lrelu(acc[j][r] + bv);
        }
    }
    __syncthreads();
    {   // y2[16,128] = lrelu(y1 @ Wb^T + bb); wave handles 16 cols
        f32x4 acc[1] = {};
        #pragma unroll
        for (int kk = 0; kk < 8; ++kk) {
            f16x8 af = *(const f16x8*)&y1s[m15 * 264 + kk * 32 + q * 8];
            int n = wave * 16 + m15;
            f16x8 bf = *(const f16x8*)&Wb[(size_t)n * 256 + kk * 32 + q * 8];
            acc[0] = __builtin_amdgcn_mfma_f32_16x16x32_f16(af, bf, acc[0], 0, 0, 0);
        }
        int col = wave * 16 + m15;
        float bv = bb[col];
        #pragma unroll
        for (int r = 0; r < 4; ++r)
            y2s[(q * 4 + r) * 136 + col] = (_Float16)lrelu(acc[0][r] + bv);
    }
    __syncthreads();
    if (tid < 32) {   // y3: 16 batches x 2 outs, tanh; out is cached (host-read only)
        int r = tid >> 1, o = tid & 1;
        float acc = cb[o];
        #pragma unroll 8
        for (int k = 0; k < 128; ++k)
            acc += (float)Wc[o * 128 + k] * (float)y2s[r * 136 + k];
        out[((size_t)(b0 + r) * TT + t) * 2 + o] = tanhf(acc);
    }
}

// ---------------------------------------------------------------- persistent decoder
struct DecP {
    const _Float16* encH;
    const float* z;
    _Float16* eb;
    const _Float16* Wfc1;  const float* biasf;
    const _Float16* L1W;   const float* L1b;
    const _Float16* L2W;   const float* L2b;
    const _Float16* C_h;   const float* d_f;  const _Float16* d_h;
    const _Float16* fa;    const float* fab;
    const _Float16* fb;    const float* fbb;
    const _Float16* fcw;   const float* fcb;
    _Float16* xh1[2];  _Float16* xh2[2];  _Float16* h2n;  _Float16* G;
    float* out;
    unsigned* bars;
};

__global__ __launch_bounds__(512, 2) void decoder(DecP p) {
    __shared__ __align__(16) char smem[122880];   // [encP 51200][scratch 71680]
    char* scratch = smem + 51200;
    const int blk = blockIdx.x, tid = threadIdx.x;
    const int grp = blk >> 4, sub = blk & 15;   // 16 groups x 16 blocks; group owns 64 batches
    const int b0a = blk * 4;                    // this block's 4 attn batches
    const int bm0 = grp * 64;                   // GEMM row tile
    float c1r[8] = {}, c2r[8] = {};
    u32x4 er[3][7];                             // persistent enc, batches b0a+1..3
    unsigned want = 0;
    {   // one-time enc load: batch b0a -> persistent LDS, b0a+1..3 -> registers
        const u32x4* s0 = (const u32x4*)(p.encH + (size_t)b0a * (SEQ * ENC));
        u32x4* encP = (u32x4*)smem;
        #pragma unroll
        for (int k = 0; k < 6; ++k) encP[tid + k * 512] = s0[tid + k * 512];
        if (tid < 128) encP[tid + 3072] = s0[tid + 3072];
        #pragma unroll
        for (int i = 0; i < 3; ++i) {
            const u32x4* si = (const u32x4*)(p.encH + (size_t)(b0a + 1 + i) * (SEQ * ENC));
            #pragma unroll
            for (int k = 0; k < 6; ++k) er[i][k] = si[tid + k * 512];
            if (tid < 128) er[i][6] = si[tid + 3072];
        }
    }
    if (tid < 128) {   // G(0) = broadcast d (q-proj of h2=0); 16B bypass stores
        u32x4 v = *(const u32x4*)&p.d_h[tid * 8];
        #pragma unroll
        for (int i = 0; i < 4; ++i)
            st_sc_b128(&p.G[(size_t)(b0a + i) * 1024 + tid * 8], v);
    }
    wait_vm0();
    __syncthreads();
    for (int t = 0; t < TT; ++t) {
        const int pt = t & 1;
        // A: attention (enc from persistent LDS/registers; zero global enc reads)
        attn_phase(smem, er, p.G, p.z, p.eb, b0a, t);
        gbar(p.bars, grp, sub, ++want);
        // B: fc1 = lrelu(eb @ Wfc1^T + biasf) -> xh1[pt][:, :512]
        {
            f32x4 acc[1] = {};
            gemm_core_db<512, 64, 32, 64, 16, 16, true>(scratch, p.eb, 1088, p.Wfc1, 1088, 1088,
                                                        bm0, sub * 32, acc);
            epi_staged<512, 64, 32, 16, 16, 1>(scratch, acc, p.biasf, p.xh1[pt], 1024, bm0, sub * 32);
        }
        gbar(p.bars, grp, sub, ++want);
        // C: LSTM1, X = xh1[pt]; h1(t) -> xh2[pt][:, :512] and xh1[pt^1][:, 512:]
        lstm_phase(scratch, p.xh1[pt], p.L1W, p.L1b, c1r,
                   p.xh2[pt], 1024, p.xh1[pt ^ 1] + 512, 1024, bm0, sub * 128);
        gbar(p.bars, grp, sub, ++want);
        // D: LSTM2, X = xh2[pt]; h2(t) -> h2n and xh2[pt^1][:, 512:]
        lstm_phase(scratch, p.xh2[pt], p.L2W, p.L2b, c2r,
                   p.h2n, 512, p.xh2[pt ^ 1] + 512, 1024, bm0, sub * 128);
        gbar(p.bars, grp, sub, ++want);
        // E: q-projection for next step (skip on last) + fc2 output
        if (t < TT - 1) {
            f32x4 acc[2] = {};
            gemm_core_db<512, 64, 64, 128, 16, 32, true>(scratch, p.h2n, 512, p.C_h, 512, 512,
                                                         bm0, sub * 64, acc);
            epi_staged<512, 64, 64, 16, 32, 0>(scratch, acc, p.d_f, p.G, 1024, bm0, sub * 64);
        }
        if (sub < 4)
            fc2_512(scratch, p.h2n, p.fa, p.fab, p.fb, p.fbb, p.fcw, p.fcb,
                    p.out, bm0 + sub * 16, t);
        if (t < TT - 1) gbar(p.bars, grp, sub, ++want);
    }
}

// ---------------------------------------------------------------- launch
extern "C" void kernel_launch(void* const* d_in, const int* in_sizes, int n_in,
                              void* d_out, int out_size, void* d_ws, size_t ws_size,
                              hipStream_t stream) {
    const float* encoded = (const float*)d_in[0];
    const float* z       = (const float*)d_in[1];
    const float* q_w     = (const float*)d_in[2];
    const float* k_w     = (const float*)d_in[3];
    const float* v_w     = (const float*)d_in[4];
    const float* q_b     = (const float*)d_in[5];
    // d_in[6] (k_b): softmax-invariant — dropped exactly.
    const float* v_b     = (const float*)d_in[7];
    const float* out_w   = (const float*)d_in[8];
    const float* out_b   = (const float*)d_in[9];
    const float* fc1_w   = (const float*)d_in[10];
    const float* fc1_b   = (const float*)d_in[11];
    const float* l1_wih  = (const float*)d_in[12];
    const float* l1_whh  = (const float*)d_in[13];
    const float* l1_bih  = (const float*)d_in[14];
    const float* l1_bhh  = (const float*)d_in[15];
    const float* l2_wih  = (const float*)d_in[16];
    const float* l2_whh  = (const float*)d_in[17];
    const float* l2_bih  = (const float*)d_in[18];
    const float* l2_bhh  = (const float*)d_in[19];
    const float* fc2a_w  = (const float*)d_in[20];
    const float* fc2a_b  = (const float*)d_in[21];
    const float* fc2b_w  = (const float*)d_in[22];
    const float* fc2b_b  = (const float*)d_in[23];
    const float* fc2c_w  = (const float*)d_in[24];
    const float* fc2c_b  = (const float*)d_in[25];
    float* out = (float*)d_out;

    char* p = (char*)d_ws;
    auto take = [&](size_t bytes) { char* r = p; p += (bytes + 255) & ~(size_t)255; return r; };
    _Float16* encH  = (_Float16*)take(52428800);   // [1024,100,256] fp16
    _Float16* C_h   = (_Float16*)take(1048576);    // [1024,512]
    _Float16* Wfc1  = (_Float16*)take(1114112);    // [512,1088]
    _Float16* L1W   = (_Float16*)take(4194304);    // [2048,1024] rows h*4+g
    _Float16* L2W   = (_Float16*)take(4194304);
    _Float16* fc2a16= (_Float16*)take(262144);     // [256,512]
    _Float16* fc2b16= (_Float16*)take(65536);      // [128,256]
    _Float16* fc2c16= (_Float16*)take(512);        // [2,128]
    _Float16* eb    = (_Float16*)take(2228224);    // [1024,1088]
    _Float16* h2n   = (_Float16*)take(1048576);    // [1024,512]  h2(t)
    char* zreg = p;                                // ---- zero region (8 MB + 4 KB) ----
    _Float16* xh1a = (_Float16*)take(2097152);     // [1024,1024] = [fc1out | h1], parity 0
    _Float16* xh1b = (_Float16*)take(2097152);     // parity 1
    _Float16* xh2a = (_Float16*)take(2097152);     // [1024,1024] = [h1 | h2], parity 0
    _Float16* xh2b = (_Float16*)take(2097152);     // parity 1
    unsigned* bars = (unsigned*)take(4096);        // per-group barrier slots
    // ---- end zero region ----
    _Float16* G   = (_Float16*)take(2097152);      // [1024,1024] (init in-kernel)
    float* A      = (float*)take(1048576);
    float* d_f    = (float*)take(4096);
    _Float16* d_h = (_Float16*)take(2048);
    float* biasf  = (float*)take(2048);
    float* L1b    = (float*)take(8192);
    float* L2b    = (float*)take(8192);
    (void)in_sizes; (void)n_in; (void)out_size; (void)ws_size;

    zero_ws<<<2049, 256, 0, stream>>>((uint4*)zreg);   // 4 h-buffers + bars
    conv_enc<<<25600, 256, 0, stream>>>((const float4*)encoded, (f16x4*)encH);
    prep_qk<<<1024, 256, 0, stream>>>(k_w, q_w, q_b, C_h, d_f, d_h);
    prep_A<<<512, 256, 0, stream>>>(fc1_w, out_w, A);
    prep_wfc1<<<512, 256, 0, stream>>>(A, v_w, v_b, fc1_w, out_b, fc1_b, Wfc1, biasf);
    prep_lstm<<<8192, 256, 0, stream>>>(l1_wih, l1_whh, l1_bih, l1_bhh, L1W, L1b);
    prep_lstm<<<8192, 256, 0, stream>>>(l2_wih, l2_whh, l2_bih, l2_bhh, L2W, L2b);
    prep_fc2c<<<641, 256, 0, stream>>>(fc2a_w, fc2b_w, fc2c_w, fc2a16, fc2b16, fc2c16);

    DecP dp;
    dp.encH = encH; dp.z = z; dp.eb = eb;
    dp.Wfc1 = Wfc1; dp.biasf = biasf;
    dp.L1W = L1W; dp.L1b = L1b; dp.L2W = L2W; dp.L2b = L2b;
    dp.C_h = C_h; dp.d_f = d_f; dp.d_h = d_h;
    dp.fa = fc2a16; dp.fab = fc2a_b; dp.fb = fc2b16; dp.fbb = fc2b_b;
    dp.fcw = fc2c16; dp.fcb = fc2c_b;
    dp.xh1[0] = xh1a; dp.xh1[1] = xh1b;
    dp.xh2[0] = xh2a; dp.xh2[1] = xh2b;
    dp.h2n = h2n; dp.G = G;
    dp.out = out; dp.bars = bars;
    void* params[] = { &dp };
    // Cooperative launch guarantees co-residency for the in-kernel barrier.
    // 256 blocks x 512 thr, 122880 B LDS -> 1 block/CU, always satisfiable.
    if (hipLaunchCooperativeKernel((const void*)decoder, dim3(256), dim3(512),
                                   params, 0, stream) != hipSuccess) {
        // Fallback: plain launch. grid(256) <= #CUs => all workgroups resident
        // at dispatch; per-group barrier remains safe.
        decoder<<<256, 512, 0, stream>>>(dp);
    }
}